// Round 10
// baseline (267.382 us; speedup 1.0000x reference)
//
#include <hip/hip_runtime.h>
#include <hip/hip_bf16.h>
#include <math.h>

// ---------------- problem constants ----------------
#define BATCH 65536
#define NT 512
#define BM 32

using f32x4 = __attribute__((ext_vector_type(4))) float;
using s16x8 = __attribute__((ext_vector_type(8))) short;

#define MFMA16(a, b, c) __builtin_amdgcn_mfma_f32_16x16x32_bf16((a), (b), (c), 0, 0, 0)

__device__ __forceinline__ unsigned short f2bf(float f) {
    unsigned u = __builtin_bit_cast(unsigned, f);
    u = u + 0x7FFFu + ((u >> 16) & 1u);   // RNE
    return (unsigned short)(u >> 16);
}
__device__ __forceinline__ float bf2f(unsigned short h) {
    unsigned u = ((unsigned)h) << 16;
    return __builtin_bit_cast(float, u);
}

// A&S 7.1.26 erf, branchless, err 1.5e-7
__device__ __forceinline__ float fast_erf(float x) {
    float ax = fabsf(x);
    float t = __builtin_amdgcn_rcpf(fmaf(0.3275911f, ax, 1.0f));
    float poly = t * fmaf(t, fmaf(t, fmaf(t, fmaf(t, 1.061405429f, -1.453152027f),
                                          1.421413741f), -0.284496736f), 0.254829592f);
    float r = 1.0f - poly * __expf(-ax * ax);
    return copysignf(r, x);
}
__device__ __forceinline__ float gelu(float y) {
    return 0.5f * y * (1.0f + fast_erf(y * 0.70710678118654752f));
}

// swizzled LDS addressing: HBUF rows 1024B; 16B granule XOR (row&7)
__device__ __forceinline__ int hswz(int row, int k) {
    return row * 1024 + ((((k >> 3) ^ (row & 7))) << 4) + ((k & 7) << 1);
}
__device__ __forceinline__ int xaddr(int base, int row, int k) {
    return base + row * 128 + ((((k >> 3) ^ (row & 7))) << 4) + ((k & 7) << 1);
}

// ---------------- weights prep: f32 [K][N] -> bf16 [N][K] ----------------
__global__ void weights_kernel(const float* __restrict__ W1, const float* __restrict__ W2,
                               const float* __restrict__ W3, unsigned short* __restrict__ wt) {
    __shared__ unsigned short tile[32][33];
    int b = blockIdx.x;
    const float* src; unsigned short* dst; int K, N, kt, nt;
    if (b < 32)       { src = W1; dst = wt;          K = 64;  N = 512; kt = b >> 4;        nt = b & 15; }
    else if (b < 288) { int c = b - 32;  src = W2; dst = wt + 32768;  K = 512; N = 512; kt = c >> 4; nt = c & 15; }
    else              { int c = b - 288; src = W3; dst = wt + 294912; K = 512; N = 64;  kt = c >> 1; nt = c & 1;  }
    int tx = threadIdx.x & 31, ty = threadIdx.x >> 5;
    int k0 = kt * 32, n0 = nt * 32;
#pragma unroll
    for (int i = 0; i < 4; i++) {
        int k = k0 + ty + i * 8;
        tile[tx][ty + i * 8] = f2bf(src[(size_t)k * N + n0 + tx]);
    }
    __syncthreads();
#pragma unroll
    for (int i = 0; i < 4; i++) {
        int n = n0 + ty + i * 8;
        dst[(size_t)n * K + k0 + tx] = tile[ty + i * 8][tx];
    }
}

// ---------------- shared LN partial helpers (row-split, 8 waves) ----------------
__device__ __forceinline__ void ln_partials(f32x4 (&acc)[2][4], char* smem, int redb,
                                            int ln, int g, int wave) {
#pragma unroll
    for (int fm = 0; fm < 2; fm++)
#pragma unroll
        for (int r = 0; r < 4; r++) {
            float s = 0.f, q = 0.f;
#pragma unroll
            for (int fn = 0; fn < 4; fn++) { float v = acc[fm][fn][r]; s += v; q += v * v; }
#pragma unroll
            for (int m = 1; m < 16; m <<= 1) { s += __shfl_xor(s, m, 64); q += __shfl_xor(q, m, 64); }
            if (ln == 0) {
                int row = fm * 16 + g * 4 + r;
                float* rp = (float*)(smem + redb + (row * 8 + wave) * 8);
                rp[0] = s; rp[1] = q;
            }
        }
}

// =========================================================================
// K1: GEMM1 + LN1 + GELU -> h1 (bf16, row-major [rows][512])
// LDS: HBUF 32KB | XBUF @32768 (4KB) | REDB @36864 (2KB) | STATB @38912
// =========================================================================
#define SMEM_K1 39168
__global__ __launch_bounds__(NT, 6) void k1_gemm1(
    const float* __restrict__ shift_bits,
    const float* __restrict__ b1, const float* __restrict__ g1, const float* __restrict__ be1,
    const unsigned short* __restrict__ wt, unsigned short* __restrict__ h1,
    int rowoff) {
    __shared__ char smem[SMEM_K1];
    const int t = threadIdx.x;
    const int wave = t >> 6, lane = t & 63, g = lane >> 4, ln = lane & 15;
    const int row0 = rowoff + blockIdx.x * BM;
    const int lrow0 = blockIdx.x * BM;      // local row in h1 buffer
    const int n0w = wave * 64;
    const int XB = 32768, RB = 36864, SB = 38912;
    const unsigned short* wt1 = wt;

    // stage shift_bits (32x64 f32 -> bf16 swizzled 128B rows)
    {
        int r = t >> 4, c = t & 15;
        float4 x = *(const float4*)(shift_bits + (size_t)(row0 + r) * 64 + c * 4);
        unsigned p0 = (unsigned)f2bf(x.x) | ((unsigned)f2bf(x.y) << 16);
        unsigned p1 = (unsigned)f2bf(x.z) | ((unsigned)f2bf(x.w) << 16);
        uint2 v; v.x = p0; v.y = p1;
        *(uint2*)(smem + XB + r * 128 + (((c >> 1) ^ (r & 7)) << 4) + (c & 1) * 8) = v;
    }
    __syncthreads();

    // GEMM1: x(32x64) @ W1(64x512) -> acc[2][4]
    f32x4 acc[2][4];
#pragma unroll
    for (int fm = 0; fm < 2; fm++)
#pragma unroll
        for (int fn = 0; fn < 4; fn++) acc[fm][fn] = (f32x4){0.f, 0.f, 0.f, 0.f};
#pragma unroll
    for (int ks = 0; ks < 2; ks++) {
        s16x8 af[2], bf[4];
#pragma unroll
        for (int fn = 0; fn < 4; fn++)
            bf[fn] = *(const s16x8*)(wt1 + (size_t)(n0w + fn * 16 + ln) * 64 + ks * 32 + g * 8);
#pragma unroll
        for (int fm = 0; fm < 2; fm++)
            af[fm] = *(const s16x8*)(smem + xaddr(XB, fm * 16 + ln, ks * 32 + g * 8));
#pragma unroll
        for (int fm = 0; fm < 2; fm++)
#pragma unroll
            for (int fn = 0; fn < 4; fn++) acc[fm][fn] = MFMA16(af[fm], bf[fn], acc[fm][fn]);
    }

    // + bias, partials
    {
        float bb[4];
#pragma unroll
        for (int fn = 0; fn < 4; fn++) bb[fn] = b1[n0w + fn * 16 + ln];
#pragma unroll
        for (int fm = 0; fm < 2; fm++)
#pragma unroll
            for (int fn = 0; fn < 4; fn++)
#pragma unroll
                for (int r = 0; r < 4; r++) acc[fm][fn][r] += bb[fn];
    }
    ln_partials(acc, smem, RB, ln, g, wave);
    __syncthreads();
    if (t < 32) {
        float s = 0.f, q = 0.f;
#pragma unroll
        for (int w = 0; w < 8; w++) {
            float* rp = (float*)(smem + RB + (t * 8 + w) * 8);
            s += rp[0]; q += rp[1];
        }
        float mu = s * (1.0f / 512.0f);
        float var = q * (1.0f / 512.0f) - mu * mu;
        float rs = rsqrtf(var + 1e-5f);
        float* sp = (float*)(smem + SB + t * 8);
        sp[0] = mu; sp[1] = rs;
    }
    __syncthreads();
    // LN apply + GELU -> HBUF (swizzled bf16)
    {
        float gm[4], bt[4];
#pragma unroll
        for (int fn = 0; fn < 4; fn++) { int c = n0w + fn * 16 + ln; gm[fn] = g1[c]; bt[fn] = be1[c]; }
#pragma unroll
        for (int fm = 0; fm < 2; fm++)
#pragma unroll
            for (int r = 0; r < 4; r++) {
                int row = fm * 16 + g * 4 + r;
                float* sp = (float*)(smem + SB + row * 8);
                float mu = sp[0], rs = sp[1];
#pragma unroll
                for (int fn = 0; fn < 4; fn++) {
                    int col = n0w + fn * 16 + ln;
                    float y = (acc[fm][fn][r] - mu) * rs * gm[fn] + bt[fn];
                    *(unsigned short*)(smem + hswz(row, col)) = f2bf(gelu(y));
                }
            }
    }
    __syncthreads();
    // coalesced copy-out: un-swizzle -> row-major h1
    {
        int r = t >> 4, c0 = (t & 15) * 32;
        unsigned short* dst = h1 + (size_t)(lrow0 + r) * 512 + c0;
#pragma unroll
        for (int j = 0; j < 4; j++) {
            int gr = (c0 >> 3) + j;
            uint4 v = *(const uint4*)(smem + r * 1024 + ((gr ^ (r & 7)) << 4));
            *(uint4*)(dst + j * 8) = v;
        }
    }
}

// =========================================================================
// K2: GEMM2 -> h2_pre (bf16, biased, PRE-LN) + per-row stats (mu, rs)
// LDS: HBUF 32KB | REDB @32768 (2KB)
// =========================================================================
#define SMEM_K2 34816
__global__ __launch_bounds__(NT, 6) void k2_gemm2(
    const unsigned short* __restrict__ h1, const float* __restrict__ b2,
    const unsigned short* __restrict__ wt, unsigned short* __restrict__ h2,
    float* __restrict__ stats, int rowoff) {
    __shared__ char smem[SMEM_K2];
    const int t = threadIdx.x;
    const int wave = t >> 6, lane = t & 63, g = lane >> 4, ln = lane & 15;
    const int lrow0 = blockIdx.x * BM;
    const int n0w = wave * 64;
    const int RB = 32768;
    const unsigned short* wt2 = wt + 32768;

    // stage h1 tile -> HBUF (swizzled): reg-staged coalesced loads
    {
        int r = t >> 4, c0 = (t & 15) * 32;
        const unsigned short* src = h1 + (size_t)(lrow0 + r) * 512 + c0;
#pragma unroll
        for (int j = 0; j < 4; j++) {
            uint4 v = *(const uint4*)(src + j * 8);
            int gr = (c0 >> 3) + j;
            *(uint4*)(smem + r * 1024 + ((gr ^ (r & 7)) << 4)) = v;
        }
    }
    __syncthreads();

    const unsigned short* b2base[4];
#pragma unroll
    for (int fn = 0; fn < 4; fn++) b2base[fn] = wt2 + (size_t)(n0w + fn * 16 + ln) * 512;

    // GEMM2: h1(32x512) @ W2 -> acc[2][4], B from L2
    f32x4 acc[2][4];
#pragma unroll
    for (int fm = 0; fm < 2; fm++)
#pragma unroll
        for (int fn = 0; fn < 4; fn++) acc[fm][fn] = (f32x4){0.f, 0.f, 0.f, 0.f};
#pragma unroll
    for (int step = 0; step < 16; step++) {
        s16x8 af[2], bf[4];
#pragma unroll
        for (int fn = 0; fn < 4; fn++)
            bf[fn] = *(const s16x8*)(b2base[fn] + step * 32 + g * 8);
#pragma unroll
        for (int fm = 0; fm < 2; fm++)
            af[fm] = *(const s16x8*)(smem + hswz(fm * 16 + ln, step * 32 + g * 8));
#pragma unroll
        for (int fm = 0; fm < 2; fm++)
#pragma unroll
            for (int fn = 0; fn < 4; fn++) acc[fm][fn] = MFMA16(af[fm], bf[fn], acc[fm][fn]);
    }

    // + bias, partials
    {
        float bb[4];
#pragma unroll
        for (int fn = 0; fn < 4; fn++) bb[fn] = b2[n0w + fn * 16 + ln];
#pragma unroll
        for (int fm = 0; fm < 2; fm++)
#pragma unroll
            for (int fn = 0; fn < 4; fn++)
#pragma unroll
                for (int r = 0; r < 4; r++) acc[fm][fn][r] += bb[fn];
    }
    ln_partials(acc, smem, RB, ln, g, wave);
    __syncthreads();   // also: all A-reads of HBUF complete

    // stats -> global (f32 pairs), h2_pre -> HBUF (bf16 swizzled)
    if (t < 32) {
        float s = 0.f, q = 0.f;
#pragma unroll
        for (int w = 0; w < 8; w++) {
            float* rp = (float*)(smem + RB + (t * 8 + w) * 8);
            s += rp[0]; q += rp[1];
        }
        float mu = s * (1.0f / 512.0f);
        float var = q * (1.0f / 512.0f) - mu * mu;
        float rs = rsqrtf(var + 1e-5f);
        float2 sv; sv.x = mu; sv.y = rs;
        *(float2*)(stats + (size_t)(rowoff + lrow0 + t) * 2) = sv;
    }
#pragma unroll
    for (int fm = 0; fm < 2; fm++)
#pragma unroll
        for (int r = 0; r < 4; r++) {
            int row = fm * 16 + g * 4 + r;
#pragma unroll
            for (int fn = 0; fn < 4; fn++) {
                int col = n0w + fn * 16 + ln;
                *(unsigned short*)(smem + hswz(row, col)) = f2bf(acc[fm][fn][r]);
            }
        }
    __syncthreads();
    // coalesced copy-out h2_pre
    {
        int r = t >> 4, c0 = (t & 15) * 32;
        unsigned short* dst = h2 + (size_t)(lrow0 + r) * 512 + c0;
#pragma unroll
        for (int j = 0; j < 4; j++) {
            int gr = (c0 >> 3) + j;
            uint4 v = *(const uint4*)(smem + r * 1024 + ((gr ^ (r & 7)) << 4));
            *(uint4*)(dst + j * 8) = v;
        }
    }
}

// =========================================================================
// K3: LN2+GELU (fused into staging) + GEMM3 + softmax + causal conv -> out
// LDS: HBUF 32KB (h2 tile swizzled; later overlay LOGB@0 32x272B, APAD@8704 32x544B)
// =========================================================================
#define SMEM_K3 32768
__global__ __launch_bounds__(NT, 6) void k3_head(
    const unsigned short* __restrict__ h2, const float* __restrict__ stats,
    const float* __restrict__ a_bits,
    const float* __restrict__ g2, const float* __restrict__ be2,
    const float* __restrict__ b3, const unsigned short* __restrict__ wt,
    float* __restrict__ out, int rowoff) {
    __shared__ char smem[SMEM_K3];
    const int t = threadIdx.x;
    const int wave = t >> 6, lane = t & 63, g = lane >> 4, ln = lane & 15;
    const int lrow0 = blockIdx.x * BM;
    const int row0 = rowoff + lrow0;
    const unsigned short* wt3 = wt + 294912;

    // stage h2 tile with LN2+GELU applied on the fly -> HBUF swizzled bf16
    {
        int r = t >> 4, c0 = (t & 15) * 32;
        float2 st = *(const float2*)(stats + (size_t)(row0 + r) * 2);
        float mu = st.x, rs = st.y;
        const unsigned short* src = h2 + (size_t)(lrow0 + r) * 512 + c0;
#pragma unroll
        for (int j = 0; j < 4; j++) {
            uint4 v = *(const uint4*)(src + j * 8);
            const unsigned short* pv = (const unsigned short*)&v;
            unsigned short o[8];
#pragma unroll
            for (int e = 0; e < 8; e++) {
                int col = c0 + j * 8 + e;
                float y = (bf2f(pv[e]) - mu) * rs * g2[col] + be2[col];
                o[e] = f2bf(gelu(y));
            }
            int gr = (c0 >> 3) + j;
            *(uint4*)(smem + r * 1024 + ((gr ^ (r & 7)) << 4)) = *(uint4*)o;
        }
    }
    __syncthreads();

    // GEMM3: h2(32x512) @ W3(512x64): one 16x16 tile per wave (mh,q), dual acc
    const int mh = wave >> 2, q = wave & 3;
    float b3v = b3[q * 16 + ln];
    const unsigned short* b3base = wt3 + (size_t)(q * 16 + ln) * 512;
    f32x4 acc3a = (f32x4){0.f, 0.f, 0.f, 0.f};
    f32x4 acc3b = (f32x4){0.f, 0.f, 0.f, 0.f};
#pragma unroll
    for (int ks = 0; ks < 16; ks += 2) {
        s16x8 bfr0 = *(const s16x8*)(b3base + ks * 32 + g * 8);
        s16x8 bfr1 = *(const s16x8*)(b3base + (ks + 1) * 32 + g * 8);
        s16x8 af0 = *(const s16x8*)(smem + hswz(mh * 16 + ln, ks * 32 + g * 8));
        s16x8 af1 = *(const s16x8*)(smem + hswz(mh * 16 + ln, (ks + 1) * 32 + g * 8));
        acc3a = MFMA16(af0, bfr0, acc3a);
        acc3b = MFMA16(af1, bfr1, acc3b);
    }
    __syncthreads();

    // logits + zero-padded a-tile (overlay HBUF, now dead)
    const int LOGB = 0, ABUF = 8704, LST = 272, AST = 544;
#pragma unroll
    for (int r = 0; r < 4; r++) {
        int row = mh * 16 + g * 4 + r;
        *(float*)(smem + LOGB + row * LST + (q * 16 + ln) * 4) = acc3a[r] + acc3b[r] + b3v;
    }
    {
        int r = t >> 4, c0 = (t & 15) * 4;
        float* ap = (float*)(smem + ABUF + r * AST);
        float4 z4 = {0.f, 0.f, 0.f, 0.f};
        *(float4*)(ap + c0) = z4;
        float4 av = *(const float4*)(a_bits + (size_t)(row0 + r) * 64 + c0);
        *(float4*)(ap + 64 + c0) = av;
    }
    __syncthreads();

    // softmax over 64 (16 thr/row)
    {
        int r = t >> 4, c0 = (t & 15) * 4;
        float* lp = (float*)(smem + LOGB + r * LST + c0 * 4);
        float4 v = *(float4*)lp;
        float mx = fmaxf(fmaxf(v.x, v.y), fmaxf(v.z, v.w));
#pragma unroll
        for (int d = 1; d < 16; d <<= 1) mx = fmaxf(mx, __shfl_xor(mx, d, 64));
        float e0 = __expf(v.x - mx), e1 = __expf(v.y - mx);
        float e2 = __expf(v.z - mx), e3 = __expf(v.w - mx);
        float s = e0 + e1 + e2 + e3;
#pragma unroll
        for (int d = 1; d < 16; d <<= 1) s += __shfl_xor(s, d, 64);
        float inv = 1.0f / s;
        float4 o; o.x = e0 * inv; o.y = e1 * inv; o.z = e2 * inv; o.w = e3 * inv;
        *(float4*)lp = o;
    }
    __syncthreads();

    // causal conv, 16 thr/row, 4 outs/thread, zero-padded sliding window
    {
        int r = t >> 4, i0 = (t & 15) * 4;
        const float* prow = (const float*)(smem + LOGB + r * LST);
        const float* apad = (const float*)(smem + ABUF + r * AST);
        float W[8];
        {
            float4 wa = *(const float4*)(apad + i0 + 60);
            float4 wb = *(const float4*)(apad + i0 + 64);
            W[0] = wa.x; W[1] = wa.y; W[2] = wa.z; W[3] = wa.w;
            W[4] = wb.x; W[5] = wb.y; W[6] = wb.z; W[7] = wb.w;
        }
        float o0 = 0.f, o1 = 0.f, o2 = 0.f, o3 = 0.f;
#pragma unroll
        for (int s4 = 0; s4 < 16; s4++) {
            float4 p4 = *(const float4*)(prow + 4 * s4);
            o0 = fmaf(p4.x, W[4], fmaf(p4.y, W[3], fmaf(p4.z, W[2], fmaf(p4.w, W[1], o0))));
            o1 = fmaf(p4.x, W[5], fmaf(p4.y, W[4], fmaf(p4.z, W[3], fmaf(p4.w, W[2], o1))));
            o2 = fmaf(p4.x, W[6], fmaf(p4.y, W[5], fmaf(p4.z, W[4], fmaf(p4.w, W[3], o2))));
            o3 = fmaf(p4.x, W[7], fmaf(p4.y, W[6], fmaf(p4.z, W[5], fmaf(p4.w, W[4], o3))));
            if (s4 < 15) {
                W[4] = W[0]; W[5] = W[1]; W[6] = W[2]; W[7] = W[3];
                float4 nw = *(const float4*)(apad + i0 + 56 - 4 * s4);
                W[0] = nw.x; W[1] = nw.y; W[2] = nw.z; W[3] = nw.w;
            }
        }
        float4 o; o.x = o0; o.y = o1; o.z = o2; o.w = o3;
        *(float4*)(out + (size_t)(row0 + r) * 64 + i0) = o;
    }
}

extern "C" void kernel_launch(void* const* d_in, const int* in_sizes, int n_in,
                              void* d_out, int out_size, void* d_ws, size_t ws_size,
                              hipStream_t stream) {
    const float* a_bits = (const float*)d_in[0];
    const float* shift  = (const float*)d_in[1];
    const float* W1  = (const float*)d_in[2];
    const float* b1  = (const float*)d_in[3];
    const float* g1  = (const float*)d_in[4];
    const float* be1 = (const float*)d_in[5];
    const float* W2  = (const float*)d_in[6];
    const float* b2  = (const float*)d_in[7];
    const float* g2  = (const float*)d_in[8];
    const float* be2 = (const float*)d_in[9];
    const float* W3  = (const float*)d_in[10];
    const float* b3  = (const float*)d_in[11];
    float* out = (float*)d_out;

    // workspace layout (bytes):
    //   wt    [0, 655360)          bf16 x 327680
    //   stats [655360, 1179648)    f32 x (BATCH*2)
    //   h1    [1179648, +chunk*1024)
    //   h2    [h1_end,  +chunk*1024)
    char* ws = (char*)d_ws;
    unsigned short* wt = (unsigned short*)ws;
    float* stats = (float*)(ws + 655360);

    // deterministic chunk selection from ws_size
    int CH = 1;
    while (CH < 32) {
        size_t need = 1179648ull + 2048ull * (size_t)(BATCH / CH);
        if (need <= ws_size) break;
        CH *= 2;
    }
    const int chunk = BATCH / CH;
    unsigned short* h1 = (unsigned short*)(ws + 1179648);
    unsigned short* h2 = h1 + (size_t)chunk * 512;

    weights_kernel<<<320, 256, 0, stream>>>(W1, W2, W3, wt);
    for (int c = 0; c < CH; c++) {
        int rowoff = c * chunk;
        k1_gemm1<<<chunk / BM, NT, 0, stream>>>(shift, b1, g1, be1, wt, h1, rowoff);
        k2_gemm2<<<chunk / BM, NT, 0, stream>>>(h1, b2, wt, h2, stats, rowoff);
        k3_head<<<chunk / BM, NT, 0, stream>>>(h2, stats, a_bits, g2, be2, b3, wt, out, rowoff);
    }
}

// Round 11
// 184.887 us; speedup vs baseline: 1.4462x; 1.4462x over previous
//
#include <hip/hip_runtime.h>
#include <hip/hip_bf16.h>
#include <math.h>

// ---------------- problem constants ----------------
#define BATCH 65536
#define NT 512
#define BM 32

using f32x4 = __attribute__((ext_vector_type(4))) float;
using s16x8 = __attribute__((ext_vector_type(8))) short;

#define MFMA16(a, b, c) __builtin_amdgcn_mfma_f32_16x16x32_bf16((a), (b), (c), 0, 0, 0)

__device__ __forceinline__ unsigned short f2bf(float f) {
    unsigned u = __builtin_bit_cast(unsigned, f);
    u = u + 0x7FFFu + ((u >> 16) & 1u);   // RNE
    return (unsigned short)(u >> 16);
}
__device__ __forceinline__ float bf2f(unsigned short h) {
    unsigned u = ((unsigned)h) << 16;
    return __builtin_bit_cast(float, u);
}

// A&S 7.1.26 erf, branchless, err 1.5e-7
__device__ __forceinline__ float fast_erf(float x) {
    float ax = fabsf(x);
    float t = __builtin_amdgcn_rcpf(fmaf(0.3275911f, ax, 1.0f));
    float poly = t * fmaf(t, fmaf(t, fmaf(t, fmaf(t, 1.061405429f, -1.453152027f),
                                          1.421413741f), -0.284496736f), 0.254829592f);
    float r = 1.0f - poly * __expf(-ax * ax);
    return copysignf(r, x);
}
__device__ __forceinline__ float gelu(float y) {
    return 0.5f * y * (1.0f + fast_erf(y * 0.70710678118654752f));
}

// swizzled LDS addressing: HBUF rows 1024B; 16B granule XOR (row&7)
__device__ __forceinline__ int hswz(int row, int k) {
    return row * 1024 + ((((k >> 3) ^ (row & 7))) << 4) + ((k & 7) << 1);
}
__device__ __forceinline__ int xaddr(int base, int row, int k) {
    return base + row * 128 + ((((k >> 3) ^ (row & 7))) << 4) + ((k & 7) << 1);
}

// ---------------- weights prep: fragment-linearized bf16 layout ----------------
// frag(nt, ks) element(lane, e) = W[k = ks*32 + (lane>>4)*8 + e][n = nt*16 + (lane&15)]
// stored contiguously: dst[(fragidx*64 + lane)*8 + e]  -> one 1KB coalesced block/frag.
// wt1f @ elem 0      : 64 frags  (nt 0..31, ks 0..1)   from W1 [64][512]
// wt2f @ elem 32768  : 512 frags (nt 0..31, ks 0..15)  from W2 [512][512]
// wt3f @ elem 294912 : 64 frags  (nt 0..3,  ks 0..15)  from W3 [512][64]
__global__ void weights_frag(const float* __restrict__ W1, const float* __restrict__ W2,
                             const float* __restrict__ W3, unsigned short* __restrict__ wt) {
    int b = blockIdx.x;
    int lane = threadIdx.x;                 // 64 threads
    const float* src; unsigned short* dst; int N, fragidx;
    if (b < 64)       { src = W1; dst = wt;          N = 512; fragidx = b; }
    else if (b < 576) { src = W2; dst = wt + 32768;  N = 512; fragidx = b - 64; }
    else              { src = W3; dst = wt + 294912; N = 64;  fragidx = b - 576; }
    int nt, ks;
    if (b < 64) { nt = fragidx >> 1; ks = fragidx & 1; }
    else        { nt = fragidx >> 4; ks = fragidx & 15; }
    int n  = nt * 16 + (lane & 15);
    int k0 = ks * 32 + (lane >> 4) * 8;
    unsigned short o[8];
#pragma unroll
    for (int e = 0; e < 8; e++) o[e] = f2bf(src[(size_t)(k0 + e) * N + n]);
    *(uint4*)(dst + ((size_t)fragidx * 64 + lane) * 8) = *(uint4*)o;
}

// ---------------- shared LN partial helper (8 waves) ----------------
__device__ __forceinline__ void ln_partials(f32x4 (&acc)[2][4], char* smem, int redb,
                                            int ln, int g, int wave) {
#pragma unroll
    for (int fm = 0; fm < 2; fm++)
#pragma unroll
        for (int r = 0; r < 4; r++) {
            float s = 0.f, q = 0.f;
#pragma unroll
            for (int fn = 0; fn < 4; fn++) { float v = acc[fm][fn][r]; s += v; q += v * v; }
#pragma unroll
            for (int m = 1; m < 16; m <<= 1) { s += __shfl_xor(s, m, 64); q += __shfl_xor(q, m, 64); }
            if (ln == 0) {
                int row = fm * 16 + g * 4 + r;
                float* rp = (float*)(smem + redb + (row * 8 + wave) * 8);
                rp[0] = s; rp[1] = q;
            }
        }
}

// =========================================================================
// K1: GEMM1 + LN1 + GELU -> h1 (bf16 row-major [rows][512])
// =========================================================================
#define SMEM_K1 39168
__global__ __launch_bounds__(NT, 6) void k1_gemm1(
    const float* __restrict__ shift_bits,
    const float* __restrict__ b1, const float* __restrict__ g1, const float* __restrict__ be1,
    const unsigned short* __restrict__ wt, unsigned short* __restrict__ h1,
    int rowoff) {
    __shared__ char smem[SMEM_K1];
    const int t = threadIdx.x;
    const int wave = t >> 6, lane = t & 63, g = lane >> 4, ln = lane & 15;
    const int row0 = rowoff + blockIdx.x * BM;
    const int lrow0 = blockIdx.x * BM;
    const int n0w = wave * 64;
    const int XB = 32768, RB = 36864, SB = 38912;
    const unsigned short* wt1f = wt;

    // stage shift_bits (32x64 f32 -> bf16 swizzled 128B rows)
    {
        int r = t >> 4, c = t & 15;
        float4 x = *(const float4*)(shift_bits + (size_t)(row0 + r) * 64 + c * 4);
        unsigned p0 = (unsigned)f2bf(x.x) | ((unsigned)f2bf(x.y) << 16);
        unsigned p1 = (unsigned)f2bf(x.z) | ((unsigned)f2bf(x.w) << 16);
        uint2 v; v.x = p0; v.y = p1;
        *(uint2*)(smem + XB + r * 128 + (((c >> 1) ^ (r & 7)) << 4) + (c & 1) * 8) = v;
    }
    __syncthreads();

    // GEMM1: coalesced frag B loads
    f32x4 acc[2][4];
#pragma unroll
    for (int fm = 0; fm < 2; fm++)
#pragma unroll
        for (int fn = 0; fn < 4; fn++) acc[fm][fn] = (f32x4){0.f, 0.f, 0.f, 0.f};
#pragma unroll
    for (int ks = 0; ks < 2; ks++) {
        s16x8 af[2], bf[4];
#pragma unroll
        for (int fn = 0; fn < 4; fn++) {
            int fragidx = (wave * 4 + fn) * 2 + ks;
            bf[fn] = *(const s16x8*)(wt1f + ((size_t)fragidx * 64 + lane) * 8);
        }
#pragma unroll
        for (int fm = 0; fm < 2; fm++)
            af[fm] = *(const s16x8*)(smem + xaddr(XB, fm * 16 + ln, ks * 32 + g * 8));
#pragma unroll
        for (int fm = 0; fm < 2; fm++)
#pragma unroll
            for (int fn = 0; fn < 4; fn++) acc[fm][fn] = MFMA16(af[fm], bf[fn], acc[fm][fn]);
    }

    // + bias, partials, stats
    {
        float bb[4];
#pragma unroll
        for (int fn = 0; fn < 4; fn++) bb[fn] = b1[n0w + fn * 16 + ln];
#pragma unroll
        for (int fm = 0; fm < 2; fm++)
#pragma unroll
            for (int fn = 0; fn < 4; fn++)
#pragma unroll
                for (int r = 0; r < 4; r++) acc[fm][fn][r] += bb[fn];
    }
    ln_partials(acc, smem, RB, ln, g, wave);
    __syncthreads();
    if (t < 32) {
        float s = 0.f, q = 0.f;
#pragma unroll
        for (int w = 0; w < 8; w++) {
            float* rp = (float*)(smem + RB + (t * 8 + w) * 8);
            s += rp[0]; q += rp[1];
        }
        float mu = s * (1.0f / 512.0f);
        float var = q * (1.0f / 512.0f) - mu * mu;
        float rs = rsqrtf(var + 1e-5f);
        float* sp = (float*)(smem + SB + t * 8);
        sp[0] = mu; sp[1] = rs;
    }
    __syncthreads();
    // LN apply + GELU -> HBUF swizzled
    {
        float gm[4], bt[4];
#pragma unroll
        for (int fn = 0; fn < 4; fn++) { int c = n0w + fn * 16 + ln; gm[fn] = g1[c]; bt[fn] = be1[c]; }
#pragma unroll
        for (int fm = 0; fm < 2; fm++)
#pragma unroll
            for (int r = 0; r < 4; r++) {
                int row = fm * 16 + g * 4 + r;
                float* sp = (float*)(smem + SB + row * 8);
                float mu = sp[0], rs = sp[1];
#pragma unroll
                for (int fn = 0; fn < 4; fn++) {
                    int col = n0w + fn * 16 + ln;
                    float y = (acc[fm][fn][r] - mu) * rs * gm[fn] + bt[fn];
                    *(unsigned short*)(smem + hswz(row, col)) = f2bf(gelu(y));
                }
            }
    }
    __syncthreads();
    // coalesced copy-out: un-swizzle -> row-major h1
    {
        int r = t >> 4, c0 = (t & 15) * 32;
        unsigned short* dst = h1 + (size_t)(lrow0 + r) * 512 + c0;
#pragma unroll
        for (int j = 0; j < 4; j++) {
            int gr = (c0 >> 3) + j;
            uint4 v = *(const uint4*)(smem + r * 1024 + ((gr ^ (r & 7)) << 4));
            *(uint4*)(dst + j * 8) = v;
        }
    }
}

// =========================================================================
// K2: GEMM2 -> h2_pre (bf16, biased, PRE-LN) + per-row stats
// (512,4): cap 128 regs -> room for depth-2 B pipeline; 2 blocks/CU.
// =========================================================================
#define SMEM_K2 34816
__global__ __launch_bounds__(NT, 4) void k2_gemm2(
    const unsigned short* __restrict__ h1, const float* __restrict__ b2,
    const unsigned short* __restrict__ wt, unsigned short* __restrict__ h2,
    float* __restrict__ stats, int rowoff) {
    __shared__ char smem[SMEM_K2];
    const int t = threadIdx.x;
    const int wave = t >> 6, lane = t & 63, g = lane >> 4, ln = lane & 15;
    const int lrow0 = blockIdx.x * BM;
    const int n0w = wave * 64;
    const int RB = 32768;
    const unsigned short* wt2f = wt + 32768;

    // stage h1 tile -> HBUF swizzled
    {
        int r = t >> 4, c0 = (t & 15) * 32;
        const unsigned short* src = h1 + (size_t)(lrow0 + r) * 512 + c0;
#pragma unroll
        for (int j = 0; j < 4; j++) {
            uint4 v = *(const uint4*)(src + j * 8);
            int gr = (c0 >> 3) + j;
            *(uint4*)(smem + r * 1024 + ((gr ^ (r & 7)) << 4)) = v;
        }
    }

    // per-fn coalesced frag bases: frag (wave*4+fn)*16 + step, each 1KB; lane*16B
    const unsigned short* bp[4];
#pragma unroll
    for (int fn = 0; fn < 4; fn++)
        bp[fn] = wt2f + ((size_t)(wave * 4 + fn) * 16 * 64 + lane) * 8;

    __syncthreads();

    // GEMM2 with depth-2 register pipeline on B
    f32x4 acc[2][4];
#pragma unroll
    for (int fm = 0; fm < 2; fm++)
#pragma unroll
        for (int fn = 0; fn < 4; fn++) acc[fm][fn] = (f32x4){0.f, 0.f, 0.f, 0.f};
    {
        s16x8 bcur[4], bnxt[4];
#pragma unroll
        for (int fn = 0; fn < 4; fn++) bcur[fn] = *(const s16x8*)(bp[fn]);
#pragma unroll
        for (int step = 0; step < 16; step++) {
            if (step < 15) {
#pragma unroll
                for (int fn = 0; fn < 4; fn++)
                    bnxt[fn] = *(const s16x8*)(bp[fn] + (size_t)(step + 1) * 512);
            }
            s16x8 af[2];
#pragma unroll
            for (int fm = 0; fm < 2; fm++)
                af[fm] = *(const s16x8*)(smem + hswz(fm * 16 + ln, step * 32 + g * 8));
#pragma unroll
            for (int fm = 0; fm < 2; fm++)
#pragma unroll
                for (int fn = 0; fn < 4; fn++) acc[fm][fn] = MFMA16(af[fm], bcur[fn], acc[fm][fn]);
#pragma unroll
            for (int fn = 0; fn < 4; fn++) bcur[fn] = bnxt[fn];
        }
    }

    // + bias, partials
    {
        float bb[4];
#pragma unroll
        for (int fn = 0; fn < 4; fn++) bb[fn] = b2[n0w + fn * 16 + ln];
#pragma unroll
        for (int fm = 0; fm < 2; fm++)
#pragma unroll
            for (int fn = 0; fn < 4; fn++)
#pragma unroll
                for (int r = 0; r < 4; r++) acc[fm][fn][r] += bb[fn];
    }
    ln_partials(acc, smem, RB, ln, g, wave);
    __syncthreads();   // all A-reads of HBUF done

    if (t < 32) {
        float s = 0.f, q = 0.f;
#pragma unroll
        for (int w = 0; w < 8; w++) {
            float* rp = (float*)(smem + RB + (t * 8 + w) * 8);
            s += rp[0]; q += rp[1];
        }
        float mu = s * (1.0f / 512.0f);
        float var = q * (1.0f / 512.0f) - mu * mu;
        float rs = rsqrtf(var + 1e-5f);
        float2 sv; sv.x = mu; sv.y = rs;
        *(float2*)(stats + (size_t)(rowoff + lrow0 + t) * 2) = sv;
    }
#pragma unroll
    for (int fm = 0; fm < 2; fm++)
#pragma unroll
        for (int r = 0; r < 4; r++) {
            int row = fm * 16 + g * 4 + r;
#pragma unroll
            for (int fn = 0; fn < 4; fn++) {
                int col = n0w + fn * 16 + ln;
                *(unsigned short*)(smem + hswz(row, col)) = f2bf(acc[fm][fn][r]);
            }
        }
    __syncthreads();
    // coalesced copy-out h2_pre
    {
        int r = t >> 4, c0 = (t & 15) * 32;
        unsigned short* dst = h2 + (size_t)(lrow0 + r) * 512 + c0;
#pragma unroll
        for (int j = 0; j < 4; j++) {
            int gr = (c0 >> 3) + j;
            uint4 v = *(const uint4*)(smem + r * 1024 + ((gr ^ (r & 7)) << 4));
            *(uint4*)(dst + j * 8) = v;
        }
    }
}

// =========================================================================
// K3: LN2+GELU (fused into staging) + GEMM3 + softmax + causal conv -> out
// =========================================================================
#define SMEM_K3 32768
__global__ __launch_bounds__(NT, 6) void k3_head(
    const unsigned short* __restrict__ h2, const float* __restrict__ stats,
    const float* __restrict__ a_bits,
    const float* __restrict__ g2, const float* __restrict__ be2,
    const float* __restrict__ b3, const unsigned short* __restrict__ wt,
    float* __restrict__ out, int rowoff) {
    __shared__ char smem[SMEM_K3];
    const int t = threadIdx.x;
    const int wave = t >> 6, lane = t & 63, g = lane >> 4, ln = lane & 15;
    const int lrow0 = blockIdx.x * BM;
    const int row0 = rowoff + lrow0;
    const unsigned short* wt3f = wt + 294912;

    // stage h2 tile with LN2+GELU on the fly -> HBUF swizzled bf16
    {
        int r = t >> 4, c0 = (t & 15) * 32;
        float2 st = *(const float2*)(stats + (size_t)(row0 + r) * 2);
        float mu = st.x, rs = st.y;
        const unsigned short* src = h2 + (size_t)(lrow0 + r) * 512 + c0;
#pragma unroll
        for (int j = 0; j < 4; j++) {
            uint4 v = *(const uint4*)(src + j * 8);
            const unsigned short* pv = (const unsigned short*)&v;
            float4 ga = *(const float4*)(g2 + c0 + j * 8);
            float4 gb = *(const float4*)(g2 + c0 + j * 8 + 4);
            float4 ba = *(const float4*)(be2 + c0 + j * 8);
            float4 bb = *(const float4*)(be2 + c0 + j * 8 + 4);
            float gv[8] = {ga.x, ga.y, ga.z, ga.w, gb.x, gb.y, gb.z, gb.w};
            float bv[8] = {ba.x, ba.y, ba.z, ba.w, bb.x, bb.y, bb.z, bb.w};
            unsigned short o[8];
#pragma unroll
            for (int e = 0; e < 8; e++) {
                float y = (bf2f(pv[e]) - mu) * rs * gv[e] + bv[e];
                o[e] = f2bf(gelu(y));
            }
            int gr = (c0 >> 3) + j;
            *(uint4*)(smem + r * 1024 + ((gr ^ (r & 7)) << 4)) = *(uint4*)o;
        }
    }
    __syncthreads();

    // GEMM3: coalesced frag B loads; one 16x16 tile per wave (mh,q), dual acc
    const int mh = wave >> 2, q = wave & 3;
    float b3v = b3[q * 16 + ln];
    const unsigned short* b3p = wt3f + ((size_t)q * 16 * 64 + lane) * 8;
    f32x4 acc3a = (f32x4){0.f, 0.f, 0.f, 0.f};
    f32x4 acc3b = (f32x4){0.f, 0.f, 0.f, 0.f};
#pragma unroll
    for (int ks = 0; ks < 16; ks += 2) {
        s16x8 bfr0 = *(const s16x8*)(b3p + (size_t)ks * 512);
        s16x8 bfr1 = *(const s16x8*)(b3p + (size_t)(ks + 1) * 512);
        s16x8 af0 = *(const s16x8*)(smem + hswz(mh * 16 + ln, ks * 32 + g * 8));
        s16x8 af1 = *(const s16x8*)(smem + hswz(mh * 16 + ln, (ks + 1) * 32 + g * 8));
        acc3a = MFMA16(af0, bfr0, acc3a);
        acc3b = MFMA16(af1, bfr1, acc3b);
    }
    __syncthreads();

    // logits + zero-padded a-tile (overlay HBUF, now dead)
    const int LOGB = 0, ABUF = 8704, LST = 272, AST = 544;
#pragma unroll
    for (int r = 0; r < 4; r++) {
        int row = mh * 16 + g * 4 + r;
        *(float*)(smem + LOGB + row * LST + (q * 16 + ln) * 4) = acc3a[r] + acc3b[r] + b3v;
    }
    {
        int r = t >> 4, c0 = (t & 15) * 4;
        float* ap = (float*)(smem + ABUF + r * AST);
        float4 z4 = {0.f, 0.f, 0.f, 0.f};
        *(float4*)(ap + c0) = z4;
        float4 av = *(const float4*)(a_bits + (size_t)(row0 + r) * 64 + c0);
        *(float4*)(ap + 64 + c0) = av;
    }
    __syncthreads();

    // softmax over 64 (16 thr/row)
    {
        int r = t >> 4, c0 = (t & 15) * 4;
        float* lp = (float*)(smem + LOGB + r * LST + c0 * 4);
        float4 v = *(float4*)lp;
        float mx = fmaxf(fmaxf(v.x, v.y), fmaxf(v.z, v.w));
#pragma unroll
        for (int d = 1; d < 16; d <<= 1) mx = fmaxf(mx, __shfl_xor(mx, d, 64));
        float e0 = __expf(v.x - mx), e1 = __expf(v.y - mx);
        float e2 = __expf(v.z - mx), e3 = __expf(v.w - mx);
        float s = e0 + e1 + e2 + e3;
#pragma unroll
        for (int d = 1; d < 16; d <<= 1) s += __shfl_xor(s, d, 64);
        float inv = 1.0f / s;
        float4 o; o.x = e0 * inv; o.y = e1 * inv; o.z = e2 * inv; o.w = e3 * inv;
        *(float4*)lp = o;
    }
    __syncthreads();

    // causal conv, 16 thr/row, 4 outs/thread, zero-padded sliding window
    {
        int r = t >> 4, i0 = (t & 15) * 4;
        const float* prow = (const float*)(smem + LOGB + r * LST);
        const float* apad = (const float*)(smem + ABUF + r * AST);
        float W[8];
        {
            float4 wa = *(const float4*)(apad + i0 + 60);
            float4 wb = *(const float4*)(apad + i0 + 64);
            W[0] = wa.x; W[1] = wa.y; W[2] = wa.z; W[3] = wa.w;
            W[4] = wb.x; W[5] = wb.y; W[6] = wb.z; W[7] = wb.w;
        }
        float o0 = 0.f, o1 = 0.f, o2 = 0.f, o3 = 0.f;
#pragma unroll
        for (int s4 = 0; s4 < 16; s4++) {
            float4 p4 = *(const float4*)(prow + 4 * s4);
            o0 = fmaf(p4.x, W[4], fmaf(p4.y, W[3], fmaf(p4.z, W[2], fmaf(p4.w, W[1], o0))));
            o1 = fmaf(p4.x, W[5], fmaf(p4.y, W[4], fmaf(p4.z, W[3], fmaf(p4.w, W[2], o1))));
            o2 = fmaf(p4.x, W[6], fmaf(p4.y, W[5], fmaf(p4.z, W[4], fmaf(p4.w, W[3], o2))));
            o3 = fmaf(p4.x, W[7], fmaf(p4.y, W[6], fmaf(p4.z, W[5], fmaf(p4.w, W[4], o3))));
            if (s4 < 15) {
                W[4] = W[0]; W[5] = W[1]; W[6] = W[2]; W[7] = W[3];
                float4 nw = *(const float4*)(apad + i0 + 56 - 4 * s4);
                W[0] = nw.x; W[1] = nw.y; W[2] = nw.z; W[3] = nw.w;
            }
        }
        float4 o; o.x = o0; o.y = o1; o.z = o2; o.w = o3;
        *(float4*)(out + (size_t)(row0 + r) * 64 + i0) = o;
    }
}

extern "C" void kernel_launch(void* const* d_in, const int* in_sizes, int n_in,
                              void* d_out, int out_size, void* d_ws, size_t ws_size,
                              hipStream_t stream) {
    const float* a_bits = (const float*)d_in[0];
    const float* shift  = (const float*)d_in[1];
    const float* W1  = (const float*)d_in[2];
    const float* b1  = (const float*)d_in[3];
    const float* g1  = (const float*)d_in[4];
    const float* be1 = (const float*)d_in[5];
    const float* W2  = (const float*)d_in[6];
    const float* b2  = (const float*)d_in[7];
    const float* g2  = (const float*)d_in[8];
    const float* be2 = (const float*)d_in[9];
    const float* W3  = (const float*)d_in[10];
    const float* b3  = (const float*)d_in[11];
    float* out = (float*)d_out;

    // workspace: wt [0,655360) | stats [655360,1179648) | h1 | h2
    char* ws = (char*)d_ws;
    unsigned short* wt = (unsigned short*)ws;
    float* stats = (float*)(ws + 655360);

    int CH = 1;
    while (CH < 32) {
        size_t need = 1179648ull + 2048ull * (size_t)(BATCH / CH);
        if (need <= ws_size) break;
        CH *= 2;
    }
    const int chunk = BATCH / CH;
    unsigned short* h1 = (unsigned short*)(ws + 1179648);
    unsigned short* h2 = h1 + (size_t)chunk * 512;

    weights_frag<<<640, 64, 0, stream>>>(W1, W2, W3, wt);
    for (int c = 0; c < CH; c++) {
        int rowoff = c * chunk;
        k1_gemm1<<<chunk / BM, NT, 0, stream>>>(shift, b1, g1, be1, wt, h1, rowoff);
        k2_gemm2<<<chunk / BM, NT, 0, stream>>>(h1, b2, wt, h2, stats, rowoff);
        k3_head<<<chunk / BM, NT, 0, stream>>>(h2, stats, a_bits, g2, be2, b3, wt, out, rowoff);
    }
}

// Round 12
// 172.161 us; speedup vs baseline: 1.5531x; 1.0739x over previous
//
#include <hip/hip_runtime.h>
#include <hip/hip_bf16.h>
#include <math.h>

// ---------------- problem constants ----------------
#define BATCH 65536
#define NT 512
#define BM 32

using f32x4 = __attribute__((ext_vector_type(4))) float;
using s16x8 = __attribute__((ext_vector_type(8))) short;

#define MFMA16(a, b, c) __builtin_amdgcn_mfma_f32_16x16x32_bf16((a), (b), (c), 0, 0, 0)

__device__ __forceinline__ unsigned short f2bf(float f) {
    unsigned u = __builtin_bit_cast(unsigned, f);
    u = u + 0x7FFFu + ((u >> 16) & 1u);   // RNE
    return (unsigned short)(u >> 16);
}
__device__ __forceinline__ float bf2f(unsigned short h) {
    unsigned u = ((unsigned)h) << 16;
    return __builtin_bit_cast(float, u);
}

// A&S 7.1.26 erf, branchless, err 1.5e-7
__device__ __forceinline__ float fast_erf(float x) {
    float ax = fabsf(x);
    float t = __builtin_amdgcn_rcpf(fmaf(0.3275911f, ax, 1.0f));
    float poly = t * fmaf(t, fmaf(t, fmaf(t, fmaf(t, 1.061405429f, -1.453152027f),
                                          1.421413741f), -0.284496736f), 0.254829592f);
    float r = 1.0f - poly * __expf(-ax * ax);
    return copysignf(r, x);
}
__device__ __forceinline__ float gelu(float y) {
    return 0.5f * y * (1.0f + fast_erf(y * 0.70710678118654752f));
}

// swizzled LDS addressing: HBUF rows 1024B; 16B granule XOR (row&7)
__device__ __forceinline__ int hswz(int row, int k) {
    return row * 1024 + ((((k >> 3) ^ (row & 7))) << 4) + ((k & 7) << 1);
}
__device__ __forceinline__ int xaddr(int base, int row, int k) {
    return base + row * 128 + ((((k >> 3) ^ (row & 7))) << 4) + ((k & 7) << 1);
}

// ---------------- weights prep: fragment-linearized bf16 layout ----------------
// frag(nt, ks) element(lane, e) = W[k = ks*32 + (lane>>4)*8 + e][n = nt*16 + (lane&15)]
// dst[(fragidx*64 + lane)*8 + e]  -> one 1KB coalesced block per fragment.
__global__ void weights_frag(const float* __restrict__ W1, const float* __restrict__ W2,
                             const float* __restrict__ W3, unsigned short* __restrict__ wt) {
    int b = blockIdx.x;
    int lane = threadIdx.x;                 // 64 threads
    const float* src; unsigned short* dst; int N, fragidx;
    if (b < 64)       { src = W1; dst = wt;          N = 512; fragidx = b; }
    else if (b < 576) { src = W2; dst = wt + 32768;  N = 512; fragidx = b - 64; }
    else              { src = W3; dst = wt + 294912; N = 64;  fragidx = b - 576; }
    int nt, ks;
    if (b < 64) { nt = fragidx >> 1; ks = fragidx & 1; }
    else        { nt = fragidx >> 4; ks = fragidx & 15; }
    int n  = nt * 16 + (lane & 15);
    int k0 = ks * 32 + (lane >> 4) * 8;
    unsigned short o[8];
#pragma unroll
    for (int e = 0; e < 8; e++) o[e] = f2bf(src[(size_t)(k0 + e) * N + n]);
    *(uint4*)(dst + ((size_t)fragidx * 64 + lane) * 8) = *(uint4*)o;
}

// ---------------- shared LN partial helper (8 waves) ----------------
__device__ __forceinline__ void ln_partials(f32x4 (&acc)[2][4], char* smem, int redb,
                                            int ln, int g, int wave) {
#pragma unroll
    for (int fm = 0; fm < 2; fm++)
#pragma unroll
        for (int r = 0; r < 4; r++) {
            float s = 0.f, q = 0.f;
#pragma unroll
            for (int fn = 0; fn < 4; fn++) { float v = acc[fm][fn][r]; s += v; q += v * v; }
#pragma unroll
            for (int m = 1; m < 16; m <<= 1) { s += __shfl_xor(s, m, 64); q += __shfl_xor(q, m, 64); }
            if (ln == 0) {
                int row = fm * 16 + g * 4 + r;
                float* rp = (float*)(smem + redb + (row * 8 + wave) * 8);
                rp[0] = s; rp[1] = q;
            }
        }
}

// =========================================================================
// K1: GEMM1 + LN1 + GELU -> h1 (bf16 row-major [rows][512])
// =========================================================================
#define SMEM_K1 39168
__global__ __launch_bounds__(NT, 6) void k1_gemm1(
    const float* __restrict__ shift_bits,
    const float* __restrict__ b1, const float* __restrict__ g1, const float* __restrict__ be1,
    const unsigned short* __restrict__ wt, unsigned short* __restrict__ h1,
    int rowoff) {
    __shared__ char smem[SMEM_K1];
    const int t = threadIdx.x;
    const int wave = t >> 6, lane = t & 63, g = lane >> 4, ln = lane & 15;
    const int row0 = rowoff + blockIdx.x * BM;
    const int lrow0 = blockIdx.x * BM;
    const int n0w = wave * 64;
    const int XB = 32768, RB = 36864, SB = 38912;
    const unsigned short* wt1f = wt;

    // stage shift_bits (32x64 f32 -> bf16 swizzled 128B rows)
    {
        int r = t >> 4, c = t & 15;
        float4 x = *(const float4*)(shift_bits + (size_t)(row0 + r) * 64 + c * 4);
        unsigned p0 = (unsigned)f2bf(x.x) | ((unsigned)f2bf(x.y) << 16);
        unsigned p1 = (unsigned)f2bf(x.z) | ((unsigned)f2bf(x.w) << 16);
        uint2 v; v.x = p0; v.y = p1;
        *(uint2*)(smem + XB + r * 128 + (((c >> 1) ^ (r & 7)) << 4) + (c & 1) * 8) = v;
    }
    __syncthreads();

    f32x4 acc[2][4];
#pragma unroll
    for (int fm = 0; fm < 2; fm++)
#pragma unroll
        for (int fn = 0; fn < 4; fn++) acc[fm][fn] = (f32x4){0.f, 0.f, 0.f, 0.f};
#pragma unroll
    for (int ks = 0; ks < 2; ks++) {
        s16x8 af[2], bf[4];
#pragma unroll
        for (int fn = 0; fn < 4; fn++) {
            int fragidx = (wave * 4 + fn) * 2 + ks;
            bf[fn] = *(const s16x8*)(wt1f + ((size_t)fragidx * 64 + lane) * 8);
        }
#pragma unroll
        for (int fm = 0; fm < 2; fm++)
            af[fm] = *(const s16x8*)(smem + xaddr(XB, fm * 16 + ln, ks * 32 + g * 8));
#pragma unroll
        for (int fm = 0; fm < 2; fm++)
#pragma unroll
            for (int fn = 0; fn < 4; fn++) acc[fm][fn] = MFMA16(af[fm], bf[fn], acc[fm][fn]);
    }

    {
        float bb[4];
#pragma unroll
        for (int fn = 0; fn < 4; fn++) bb[fn] = b1[n0w + fn * 16 + ln];
#pragma unroll
        for (int fm = 0; fm < 2; fm++)
#pragma unroll
            for (int fn = 0; fn < 4; fn++)
#pragma unroll
                for (int r = 0; r < 4; r++) acc[fm][fn][r] += bb[fn];
    }
    ln_partials(acc, smem, RB, ln, g, wave);
    __syncthreads();
    if (t < 32) {
        float s = 0.f, q = 0.f;
#pragma unroll
        for (int w = 0; w < 8; w++) {
            float* rp = (float*)(smem + RB + (t * 8 + w) * 8);
            s += rp[0]; q += rp[1];
        }
        float mu = s * (1.0f / 512.0f);
        float var = q * (1.0f / 512.0f) - mu * mu;
        float rs = rsqrtf(var + 1e-5f);
        float* sp = (float*)(smem + SB + t * 8);
        sp[0] = mu; sp[1] = rs;
    }
    __syncthreads();
    {
        float gm[4], bt[4];
#pragma unroll
        for (int fn = 0; fn < 4; fn++) { int c = n0w + fn * 16 + ln; gm[fn] = g1[c]; bt[fn] = be1[c]; }
#pragma unroll
        for (int fm = 0; fm < 2; fm++)
#pragma unroll
            for (int r = 0; r < 4; r++) {
                int row = fm * 16 + g * 4 + r;
                float* sp = (float*)(smem + SB + row * 8);
                float mu = sp[0], rs = sp[1];
#pragma unroll
                for (int fn = 0; fn < 4; fn++) {
                    int col = n0w + fn * 16 + ln;
                    float y = (acc[fm][fn][r] - mu) * rs * gm[fn] + bt[fn];
                    *(unsigned short*)(smem + hswz(row, col)) = f2bf(gelu(y));
                }
            }
    }
    __syncthreads();
    {
        int r = t >> 4, c0 = (t & 15) * 32;
        unsigned short* dst = h1 + (size_t)(lrow0 + r) * 512 + c0;
#pragma unroll
        for (int j = 0; j < 4; j++) {
            int gr = (c0 >> 3) + j;
            uint4 v = *(const uint4*)(smem + r * 1024 + ((gr ^ (r & 7)) << 4));
            *(uint4*)(dst + j * 8) = v;
        }
    }
}

// =========================================================================
// K2: GEMM2 + LN2 + GELU -> h2 (bf16 POST-activation, row-major)
// (512,4): depth-3 B pipeline (2 steps issue-slack); LN applied in-register.
// =========================================================================
#define SMEM_K2 35072
__global__ __launch_bounds__(NT, 4) void k2_gemm2(
    const unsigned short* __restrict__ h1, const float* __restrict__ b2,
    const float* __restrict__ g2, const float* __restrict__ be2,
    const unsigned short* __restrict__ wt, unsigned short* __restrict__ h2) {
    __shared__ char smem[SMEM_K2];
    const int t = threadIdx.x;
    const int wave = t >> 6, lane = t & 63, g = lane >> 4, ln = lane & 15;
    const int lrow0 = blockIdx.x * BM;
    const int n0w = wave * 64;
    const int RB = 32768, SB = 34816;
    const unsigned short* wt2f = wt + 32768;

    // stage h1 tile -> HBUF swizzled
    {
        int r = t >> 4, c0 = (t & 15) * 32;
        const unsigned short* src = h1 + (size_t)(lrow0 + r) * 512 + c0;
#pragma unroll
        for (int j = 0; j < 4; j++) {
            uint4 v = *(const uint4*)(src + j * 8);
            int gr = (c0 >> 3) + j;
            *(uint4*)(smem + r * 1024 + ((gr ^ (r & 7)) << 4)) = v;
        }
    }

    // per-fn coalesced frag bases: frag (wave*4+fn)*16 + step (1KB each); lane*16B
    const unsigned short* bp[4];
#pragma unroll
    for (int fn = 0; fn < 4; fn++)
        bp[fn] = wt2f + ((size_t)(wave * 4 + fn) * 16 * 64 + lane) * 8;

    __syncthreads();

    // GEMM2 with depth-3 register pipeline on B (static modulo-3 indexing)
    f32x4 acc[2][4];
#pragma unroll
    for (int fm = 0; fm < 2; fm++)
#pragma unroll
        for (int fn = 0; fn < 4; fn++) acc[fm][fn] = (f32x4){0.f, 0.f, 0.f, 0.f};
    {
        s16x8 bpipe[3][4];
#pragma unroll
        for (int d = 0; d < 2; d++)
#pragma unroll
            for (int fn = 0; fn < 4; fn++)
                bpipe[d][fn] = *(const s16x8*)(bp[fn] + (size_t)d * 512);
#pragma unroll
        for (int step = 0; step < 16; step++) {
            if (step + 2 < 16) {
#pragma unroll
                for (int fn = 0; fn < 4; fn++)
                    bpipe[(step + 2) % 3][fn] = *(const s16x8*)(bp[fn] + (size_t)(step + 2) * 512);
            }
            s16x8 af[2];
#pragma unroll
            for (int fm = 0; fm < 2; fm++)
                af[fm] = *(const s16x8*)(smem + hswz(fm * 16 + ln, step * 32 + g * 8));
#pragma unroll
            for (int fm = 0; fm < 2; fm++)
#pragma unroll
                for (int fn = 0; fn < 4; fn++)
                    acc[fm][fn] = MFMA16(af[fm], bpipe[step % 3][fn], acc[fm][fn]);
        }
    }

    // + bias, LN partials -> stats in LDS
    {
        float bb[4];
#pragma unroll
        for (int fn = 0; fn < 4; fn++) bb[fn] = b2[n0w + fn * 16 + ln];
#pragma unroll
        for (int fm = 0; fm < 2; fm++)
#pragma unroll
            for (int fn = 0; fn < 4; fn++)
#pragma unroll
                for (int r = 0; r < 4; r++) acc[fm][fn][r] += bb[fn];
    }
    ln_partials(acc, smem, RB, ln, g, wave);
    __syncthreads();   // all A-reads of HBUF done
    if (t < 32) {
        float s = 0.f, q = 0.f;
#pragma unroll
        for (int w = 0; w < 8; w++) {
            float* rp = (float*)(smem + RB + (t * 8 + w) * 8);
            s += rp[0]; q += rp[1];
        }
        float mu = s * (1.0f / 512.0f);
        float var = q * (1.0f / 512.0f) - mu * mu;
        float rs = rsqrtf(var + 1e-5f);
        float* sp = (float*)(smem + SB + t * 8);
        sp[0] = mu; sp[1] = rs;
    }
    __syncthreads();

    // LN2 apply + GELU in-register -> HBUF swizzled (h2 is post-activation)
    {
        float gm[4], bt[4];
#pragma unroll
        for (int fn = 0; fn < 4; fn++) { int c = n0w + fn * 16 + ln; gm[fn] = g2[c]; bt[fn] = be2[c]; }
#pragma unroll
        for (int fm = 0; fm < 2; fm++)
#pragma unroll
            for (int r = 0; r < 4; r++) {
                int row = fm * 16 + g * 4 + r;
                float* sp = (float*)(smem + SB + row * 8);
                float mu = sp[0], rs = sp[1];
#pragma unroll
                for (int fn = 0; fn < 4; fn++) {
                    int col = n0w + fn * 16 + ln;
                    float y = (acc[fm][fn][r] - mu) * rs * gm[fn] + bt[fn];
                    *(unsigned short*)(smem + hswz(row, col)) = f2bf(gelu(y));
                }
            }
    }
    __syncthreads();
    // coalesced copy-out h2
    {
        int r = t >> 4, c0 = (t & 15) * 32;
        unsigned short* dst = h2 + (size_t)(lrow0 + r) * 512 + c0;
#pragma unroll
        for (int j = 0; j < 4; j++) {
            int gr = (c0 >> 3) + j;
            uint4 v = *(const uint4*)(smem + r * 1024 + ((gr ^ (r & 7)) << 4));
            *(uint4*)(dst + j * 8) = v;
        }
    }
}

// =========================================================================
// K3: pure-copy staging + GEMM3 + softmax + causal conv -> out
// =========================================================================
#define SMEM_K3 32768
__global__ __launch_bounds__(NT, 6) void k3_head(
    const unsigned short* __restrict__ h2, const float* __restrict__ a_bits,
    const float* __restrict__ b3, const unsigned short* __restrict__ wt,
    float* __restrict__ out, int rowoff) {
    __shared__ char smem[SMEM_K3];
    const int t = threadIdx.x;
    const int wave = t >> 6, lane = t & 63, g = lane >> 4, ln = lane & 15;
    const int lrow0 = blockIdx.x * BM;
    const int row0 = rowoff + lrow0;
    const unsigned short* wt3f = wt + 294912;

    // stage h2 tile (already post-GELU) -> HBUF swizzled: pure copy
    {
        int r = t >> 4, c0 = (t & 15) * 32;
        const unsigned short* src = h2 + (size_t)(lrow0 + r) * 512 + c0;
#pragma unroll
        for (int j = 0; j < 4; j++) {
            uint4 v = *(const uint4*)(src + j * 8);
            int gr = (c0 >> 3) + j;
            *(uint4*)(smem + r * 1024 + ((gr ^ (r & 7)) << 4)) = v;
        }
    }
    __syncthreads();

    // GEMM3: coalesced frag B loads; one 16x16 tile per wave (mh,q), dual acc
    const int mh = wave >> 2, q = wave & 3;
    float b3v = b3[q * 16 + ln];
    const unsigned short* b3p = wt3f + ((size_t)q * 16 * 64 + lane) * 8;
    f32x4 acc3a = (f32x4){0.f, 0.f, 0.f, 0.f};
    f32x4 acc3b = (f32x4){0.f, 0.f, 0.f, 0.f};
#pragma unroll
    for (int ks = 0; ks < 16; ks += 2) {
        s16x8 bfr0 = *(const s16x8*)(b3p + (size_t)ks * 512);
        s16x8 bfr1 = *(const s16x8*)(b3p + (size_t)(ks + 1) * 512);
        s16x8 af0 = *(const s16x8*)(smem + hswz(mh * 16 + ln, ks * 32 + g * 8));
        s16x8 af1 = *(const s16x8*)(smem + hswz(mh * 16 + ln, (ks + 1) * 32 + g * 8));
        acc3a = MFMA16(af0, bfr0, acc3a);
        acc3b = MFMA16(af1, bfr1, acc3b);
    }
    __syncthreads();

    // logits + zero-padded a-tile (overlay HBUF, now dead)
    const int LOGB = 0, ABUF = 8704, LST = 272, AST = 544;
#pragma unroll
    for (int r = 0; r < 4; r++) {
        int row = mh * 16 + g * 4 + r;
        *(float*)(smem + LOGB + row * LST + (q * 16 + ln) * 4) = acc3a[r] + acc3b[r] + b3v;
    }
    {
        int r = t >> 4, c0 = (t & 15) * 4;
        float* ap = (float*)(smem + ABUF + r * AST);
        float4 z4 = {0.f, 0.f, 0.f, 0.f};
        *(float4*)(ap + c0) = z4;
        float4 av = *(const float4*)(a_bits + (size_t)(row0 + r) * 64 + c0);
        *(float4*)(ap + 64 + c0) = av;
    }
    __syncthreads();

    // softmax over 64 (16 thr/row)
    {
        int r = t >> 4, c0 = (t & 15) * 4;
        float* lp = (float*)(smem + LOGB + r * LST + c0 * 4);
        float4 v = *(float4*)lp;
        float mx = fmaxf(fmaxf(v.x, v.y), fmaxf(v.z, v.w));
#pragma unroll
        for (int d = 1; d < 16; d <<= 1) mx = fmaxf(mx, __shfl_xor(mx, d, 64));
        float e0 = __expf(v.x - mx), e1 = __expf(v.y - mx);
        float e2 = __expf(v.z - mx), e3 = __expf(v.w - mx);
        float s = e0 + e1 + e2 + e3;
#pragma unroll
        for (int d = 1; d < 16; d <<= 1) s += __shfl_xor(s, d, 64);
        float inv = 1.0f / s;
        float4 o; o.x = e0 * inv; o.y = e1 * inv; o.z = e2 * inv; o.w = e3 * inv;
        *(float4*)lp = o;
    }
    __syncthreads();

    // causal conv, 16 thr/row, 4 outs/thread, zero-padded sliding window
    {
        int r = t >> 4, i0 = (t & 15) * 4;
        const float* prow = (const float*)(smem + LOGB + r * LST);
        const float* apad = (const float*)(smem + ABUF + r * AST);
        float W[8];
        {
            float4 wa = *(const float4*)(apad + i0 + 60);
            float4 wb = *(const float4*)(apad + i0 + 64);
            W[0] = wa.x; W[1] = wa.y; W[2] = wa.z; W[3] = wa.w;
            W[4] = wb.x; W[5] = wb.y; W[6] = wb.z; W[7] = wb.w;
        }
        float o0 = 0.f, o1 = 0.f, o2 = 0.f, o3 = 0.f;
#pragma unroll
        for (int s4 = 0; s4 < 16; s4++) {
            float4 p4 = *(const float4*)(prow + 4 * s4);
            o0 = fmaf(p4.x, W[4], fmaf(p4.y, W[3], fmaf(p4.z, W[2], fmaf(p4.w, W[1], o0))));
            o1 = fmaf(p4.x, W[5], fmaf(p4.y, W[4], fmaf(p4.z, W[3], fmaf(p4.w, W[2], o1))));
            o2 = fmaf(p4.x, W[6], fmaf(p4.y, W[5], fmaf(p4.z, W[4], fmaf(p4.w, W[3], o2))));
            o3 = fmaf(p4.x, W[7], fmaf(p4.y, W[6], fmaf(p4.z, W[5], fmaf(p4.w, W[4], o3))));
            if (s4 < 15) {
                W[4] = W[0]; W[5] = W[1]; W[6] = W[2]; W[7] = W[3];
                float4 nw = *(const float4*)(apad + i0 + 56 - 4 * s4);
                W[0] = nw.x; W[1] = nw.y; W[2] = nw.z; W[3] = nw.w;
            }
        }
        float4 o; o.x = o0; o.y = o1; o.z = o2; o.w = o3;
        *(float4*)(out + (size_t)(row0 + r) * 64 + i0) = o;
    }
}

extern "C" void kernel_launch(void* const* d_in, const int* in_sizes, int n_in,
                              void* d_out, int out_size, void* d_ws, size_t ws_size,
                              hipStream_t stream) {
    const float* a_bits = (const float*)d_in[0];
    const float* shift  = (const float*)d_in[1];
    const float* W1  = (const float*)d_in[2];
    const float* b1  = (const float*)d_in[3];
    const float* g1  = (const float*)d_in[4];
    const float* be1 = (const float*)d_in[5];
    const float* W2  = (const float*)d_in[6];
    const float* b2  = (const float*)d_in[7];
    const float* g2  = (const float*)d_in[8];
    const float* be2 = (const float*)d_in[9];
    const float* W3  = (const float*)d_in[10];
    const float* b3  = (const float*)d_in[11];
    float* out = (float*)d_out;

    // workspace: wt [0,655360) | h1 | h2
    char* ws = (char*)d_ws;
    unsigned short* wt = (unsigned short*)ws;

    int CH = 1;
    while (CH < 32) {
        size_t need = 655360ull + 2048ull * (size_t)(BATCH / CH);
        if (need <= ws_size) break;
        CH *= 2;
    }
    const int chunk = BATCH / CH;
    unsigned short* h1 = (unsigned short*)(ws + 655360);
    unsigned short* h2 = h1 + (size_t)chunk * 512;

    weights_frag<<<640, 64, 0, stream>>>(W1, W2, W3, wt);
    for (int c = 0; c < CH; c++) {
        int rowoff = c * chunk;
        k1_gemm1<<<chunk / BM, NT, 0, stream>>>(shift, b1, g1, be1, wt, h1, rowoff);
        k2_gemm2<<<chunk / BM, NT, 0, stream>>>(h1, b2, g2, be2, wt, h2);
        k3_head<<<chunk / BM, NT, 0, stream>>>(h2, a_bits, b3, wt, out, rowoff);
    }
}

// Round 13
// 144.259 us; speedup vs baseline: 1.8535x; 1.1934x over previous
//
#include <hip/hip_runtime.h>
#include <hip/hip_bf16.h>
#include <math.h>

// ---------------- problem constants ----------------
#define BATCH 65536
#define NT 512
#define BM 32

using f32x4 = __attribute__((ext_vector_type(4))) float;
using s16x8 = __attribute__((ext_vector_type(8))) short;

#define MFMA16(a, b, c) __builtin_amdgcn_mfma_f32_16x16x32_bf16((a), (b), (c), 0, 0, 0)

__device__ __forceinline__ unsigned short f2bf(float f) {
    unsigned u = __builtin_bit_cast(unsigned, f);
    u = u + 0x7FFFu + ((u >> 16) & 1u);   // RNE
    return (unsigned short)(u >> 16);
}

// A&S 7.1.26 erf, branchless, err 1.5e-7
__device__ __forceinline__ float fast_erf(float x) {
    float ax = fabsf(x);
    float t = __builtin_amdgcn_rcpf(fmaf(0.3275911f, ax, 1.0f));
    float poly = t * fmaf(t, fmaf(t, fmaf(t, fmaf(t, 1.061405429f, -1.453152027f),
                                          1.421413741f), -0.284496736f), 0.254829592f);
    float r = 1.0f - poly * __expf(-ax * ax);
    return copysignf(r, x);
}
__device__ __forceinline__ float gelu(float y) {
    return 0.5f * y * (1.0f + fast_erf(y * 0.70710678118654752f));
}

// swizzled LDS addressing: HBUF rows 1024B; 16B granule XOR (row&7)
__device__ __forceinline__ int hswz(int row, int k) {
    return row * 1024 + ((((k >> 3) ^ (row & 7))) << 4) + ((k & 7) << 1);
}
__device__ __forceinline__ int xaddr(int base, int row, int k) {
    return base + row * 128 + ((((k >> 3) ^ (row & 7))) << 4) + ((k & 7) << 1);
}

// ---------------- weights prep: fragment-linearized bf16 layout ----------------
// frag(nt, ks) element(lane, e) = W[k = ks*32 + (lane>>4)*8 + e][n = nt*16 + (lane&15)]
// dst[(fragidx*64 + lane)*8 + e]  -> one 1KB coalesced block per fragment.
__global__ void weights_frag(const float* __restrict__ W1, const float* __restrict__ W2,
                             const float* __restrict__ W3, unsigned short* __restrict__ wt) {
    int b = blockIdx.x;
    int lane = threadIdx.x;                 // 64 threads
    const float* src; unsigned short* dst; int N, fragidx;
    if (b < 64)       { src = W1; dst = wt;          N = 512; fragidx = b; }
    else if (b < 576) { src = W2; dst = wt + 32768;  N = 512; fragidx = b - 64; }
    else              { src = W3; dst = wt + 294912; N = 64;  fragidx = b - 576; }
    int nt, ks;
    if (b < 64) { nt = fragidx >> 1; ks = fragidx & 1; }
    else        { nt = fragidx >> 4; ks = fragidx & 15; }
    int n  = nt * 16 + (lane & 15);
    int k0 = ks * 32 + (lane >> 4) * 8;
    unsigned short o[8];
#pragma unroll
    for (int e = 0; e < 8; e++) o[e] = f2bf(src[(size_t)(k0 + e) * N + n]);
    *(uint4*)(dst + ((size_t)fragidx * 64 + lane) * 8) = *(uint4*)o;
}

// ---------------- shared LN partial helper (8 waves) ----------------
__device__ __forceinline__ void ln_partials(f32x4 (&acc)[2][4], char* smem, int redb,
                                            int ln, int g, int wave) {
#pragma unroll
    for (int fm = 0; fm < 2; fm++)
#pragma unroll
        for (int r = 0; r < 4; r++) {
            float s = 0.f, q = 0.f;
#pragma unroll
            for (int fn = 0; fn < 4; fn++) { float v = acc[fm][fn][r]; s += v; q += v * v; }
#pragma unroll
            for (int m = 1; m < 16; m <<= 1) { s += __shfl_xor(s, m, 64); q += __shfl_xor(q, m, 64); }
            if (ln == 0) {
                int row = fm * 16 + g * 4 + r;
                float* rp = (float*)(smem + redb + (row * 8 + wave) * 8);
                rp[0] = s; rp[1] = q;
            }
        }
}

// =========================================================================
// K1: GEMM1 + LN1 + GELU -> h1 (bf16 row-major [rows][512])
// =========================================================================
#define SMEM_K1 39168
__global__ __launch_bounds__(NT, 6) void k1_gemm1(
    const float* __restrict__ shift_bits,
    const float* __restrict__ b1, const float* __restrict__ g1, const float* __restrict__ be1,
    const unsigned short* __restrict__ wt, unsigned short* __restrict__ h1,
    int rowoff) {
    __shared__ char smem[SMEM_K1];
    const int t = threadIdx.x;
    const int wave = t >> 6, lane = t & 63, g = lane >> 4, ln = lane & 15;
    const int row0 = rowoff + blockIdx.x * BM;
    const int lrow0 = blockIdx.x * BM;
    const int n0w = wave * 64;
    const int XB = 32768, RB = 36864, SB = 38912;
    const unsigned short* wt1f = wt;

    // stage shift_bits (32x64 f32 -> bf16 swizzled 128B rows)
    {
        int r = t >> 4, c = t & 15;
        float4 x = *(const float4*)(shift_bits + (size_t)(row0 + r) * 64 + c * 4);
        unsigned p0 = (unsigned)f2bf(x.x) | ((unsigned)f2bf(x.y) << 16);
        unsigned p1 = (unsigned)f2bf(x.z) | ((unsigned)f2bf(x.w) << 16);
        uint2 v; v.x = p0; v.y = p1;
        *(uint2*)(smem + XB + r * 128 + (((c >> 1) ^ (r & 7)) << 4) + (c & 1) * 8) = v;
    }
    __syncthreads();

    f32x4 acc[2][4];
#pragma unroll
    for (int fm = 0; fm < 2; fm++)
#pragma unroll
        for (int fn = 0; fn < 4; fn++) acc[fm][fn] = (f32x4){0.f, 0.f, 0.f, 0.f};
#pragma unroll
    for (int ks = 0; ks < 2; ks++) {
        s16x8 af[2], bf[4];
#pragma unroll
        for (int fn = 0; fn < 4; fn++) {
            int fragidx = (wave * 4 + fn) * 2 + ks;
            bf[fn] = *(const s16x8*)(wt1f + ((size_t)fragidx * 64 + lane) * 8);
        }
#pragma unroll
        for (int fm = 0; fm < 2; fm++)
            af[fm] = *(const s16x8*)(smem + xaddr(XB, fm * 16 + ln, ks * 32 + g * 8));
#pragma unroll
        for (int fm = 0; fm < 2; fm++)
#pragma unroll
            for (int fn = 0; fn < 4; fn++) acc[fm][fn] = MFMA16(af[fm], bf[fn], acc[fm][fn]);
    }

    {
        float bb[4];
#pragma unroll
        for (int fn = 0; fn < 4; fn++) bb[fn] = b1[n0w + fn * 16 + ln];
#pragma unroll
        for (int fm = 0; fm < 2; fm++)
#pragma unroll
            for (int fn = 0; fn < 4; fn++)
#pragma unroll
                for (int r = 0; r < 4; r++) acc[fm][fn][r] += bb[fn];
    }
    ln_partials(acc, smem, RB, ln, g, wave);
    __syncthreads();
    if (t < 32) {
        float s = 0.f, q = 0.f;
#pragma unroll
        for (int w = 0; w < 8; w++) {
            float* rp = (float*)(smem + RB + (t * 8 + w) * 8);
            s += rp[0]; q += rp[1];
        }
        float mu = s * (1.0f / 512.0f);
        float var = q * (1.0f / 512.0f) - mu * mu;
        float rs = rsqrtf(var + 1e-5f);
        float* sp = (float*)(smem + SB + t * 8);
        sp[0] = mu; sp[1] = rs;
    }
    __syncthreads();
    {
        float gm[4], bt[4];
#pragma unroll
        for (int fn = 0; fn < 4; fn++) { int c = n0w + fn * 16 + ln; gm[fn] = g1[c]; bt[fn] = be1[c]; }
#pragma unroll
        for (int fm = 0; fm < 2; fm++)
#pragma unroll
            for (int r = 0; r < 4; r++) {
                int row = fm * 16 + g * 4 + r;
                float* sp = (float*)(smem + SB + row * 8);
                float mu = sp[0], rs = sp[1];
#pragma unroll
                for (int fn = 0; fn < 4; fn++) {
                    int col = n0w + fn * 16 + ln;
                    float y = (acc[fm][fn][r] - mu) * rs * gm[fn] + bt[fn];
                    *(unsigned short*)(smem + hswz(row, col)) = f2bf(gelu(y));
                }
            }
    }
    __syncthreads();
    {
        int r = t >> 4, c0 = (t & 15) * 32;
        unsigned short* dst = h1 + (size_t)(lrow0 + r) * 512 + c0;
#pragma unroll
        for (int j = 0; j < 4; j++) {
            int gr = (c0 >> 3) + j;
            uint4 v = *(const uint4*)(smem + r * 1024 + ((gr ^ (r & 7)) << 4));
            *(uint4*)(dst + j * 8) = v;
        }
    }
}

// =========================================================================
// K23: GEMM2 + LN2 + GELU (in LDS) + GEMM3 + softmax + causal conv -> out
// No h2 round-trip. (512,4): est. peak regs ~32 acc + ~75 arch <= 128 cap.
// LDS: HBUF 32KB @0 | RB @32768 (2KB) | SB @34816 (256B)
// epilogue overlay of HBUF: LOGB @0 (32x272B), ABUF @8704 (32x544B)
// =========================================================================
#define SMEM_K23 35072
__global__ __launch_bounds__(NT, 4) void k23_fused(
    const unsigned short* __restrict__ h1, const float* __restrict__ a_bits,
    const float* __restrict__ b2, const float* __restrict__ g2, const float* __restrict__ be2,
    const float* __restrict__ b3, const unsigned short* __restrict__ wt,
    float* __restrict__ out, int rowoff) {
    __shared__ char smem[SMEM_K23];
    const int t = threadIdx.x;
    const int wave = t >> 6, lane = t & 63, g = lane >> 4, ln = lane & 15;
    const int lrow0 = blockIdx.x * BM;
    const int row0 = rowoff + lrow0;
    const int RB = 32768, SB = 34816;
    const unsigned short* wt2f = wt + 32768;
    const unsigned short* wt3f = wt + 294912;

    // stage h1 tile -> HBUF swizzled
    {
        int r = t >> 4, c0 = (t & 15) * 32;
        const unsigned short* src = h1 + (size_t)(lrow0 + r) * 512 + c0;
#pragma unroll
        for (int j = 0; j < 4; j++) {
            uint4 v = *(const uint4*)(src + j * 8);
            int gr = (c0 >> 3) + j;
            *(uint4*)(smem + r * 1024 + ((gr ^ (r & 7)) << 4)) = v;
        }
    }

    const int n0w = wave * 64;
    // per-fn coalesced frag bases
    const unsigned short* bp[4];
#pragma unroll
    for (int fn = 0; fn < 4; fn++)
        bp[fn] = wt2f + ((size_t)(wave * 4 + fn) * 16 * 64 + lane) * 8;

    __syncthreads();

    // GEMM2 with depth-2 register pipeline on B
    f32x4 acc[2][4];
#pragma unroll
    for (int fm = 0; fm < 2; fm++)
#pragma unroll
        for (int fn = 0; fn < 4; fn++) acc[fm][fn] = (f32x4){0.f, 0.f, 0.f, 0.f};
    {
        s16x8 bcur[4], bnxt[4];
#pragma unroll
        for (int fn = 0; fn < 4; fn++) bcur[fn] = *(const s16x8*)(bp[fn]);
#pragma unroll
        for (int step = 0; step < 16; step++) {
            if (step < 15) {
#pragma unroll
                for (int fn = 0; fn < 4; fn++)
                    bnxt[fn] = *(const s16x8*)(bp[fn] + (size_t)(step + 1) * 512);
            }
            s16x8 af[2];
#pragma unroll
            for (int fm = 0; fm < 2; fm++)
                af[fm] = *(const s16x8*)(smem + hswz(fm * 16 + ln, step * 32 + g * 8));
#pragma unroll
            for (int fm = 0; fm < 2; fm++)
#pragma unroll
                for (int fn = 0; fn < 4; fn++) acc[fm][fn] = MFMA16(af[fm], bcur[fn], acc[fm][fn]);
#pragma unroll
            for (int fn = 0; fn < 4; fn++) bcur[fn] = bnxt[fn];
        }
    }

    // + bias, LN partials -> stats
    {
        float bb[4];
#pragma unroll
        for (int fn = 0; fn < 4; fn++) bb[fn] = b2[n0w + fn * 16 + ln];
#pragma unroll
        for (int fm = 0; fm < 2; fm++)
#pragma unroll
            for (int fn = 0; fn < 4; fn++)
#pragma unroll
                for (int r = 0; r < 4; r++) acc[fm][fn][r] += bb[fn];
    }
    ln_partials(acc, smem, RB, ln, g, wave);
    __syncthreads();   // all A-reads of HBUF done
    if (t < 32) {
        float s = 0.f, q = 0.f;
#pragma unroll
        for (int w = 0; w < 8; w++) {
            float* rp = (float*)(smem + RB + (t * 8 + w) * 8);
            s += rp[0]; q += rp[1];
        }
        float mu = s * (1.0f / 512.0f);
        float var = q * (1.0f / 512.0f) - mu * mu;
        float rs = rsqrtf(var + 1e-5f);
        float* sp = (float*)(smem + SB + t * 8);
        sp[0] = mu; sp[1] = rs;
    }
    __syncthreads();

    // LN2 apply + GELU -> HBUF swizzled (h2 lives only in LDS)
    {
        float gm[4], bt[4];
#pragma unroll
        for (int fn = 0; fn < 4; fn++) { int c = n0w + fn * 16 + ln; gm[fn] = g2[c]; bt[fn] = be2[c]; }
#pragma unroll
        for (int fm = 0; fm < 2; fm++)
#pragma unroll
            for (int r = 0; r < 4; r++) {
                int row = fm * 16 + g * 4 + r;
                float* sp = (float*)(smem + SB + row * 8);
                float mu = sp[0], rs = sp[1];
#pragma unroll
                for (int fn = 0; fn < 4; fn++) {
                    int col = n0w + fn * 16 + ln;
                    float y = (acc[fm][fn][r] - mu) * rs * gm[fn] + bt[fn];
                    *(unsigned short*)(smem + hswz(row, col)) = f2bf(gelu(y));
                }
            }
    }
    __syncthreads();

    // GEMM3: h2(32x512) @ W3(512x64); wave (mh,q) owns 16x16 tile; dual acc
    const int mh = wave >> 2, q = wave & 3;
    float b3v = b3[q * 16 + ln];
    const unsigned short* b3p = wt3f + ((size_t)q * 16 * 64 + lane) * 8;
    f32x4 acc3a = (f32x4){0.f, 0.f, 0.f, 0.f};
    f32x4 acc3b = (f32x4){0.f, 0.f, 0.f, 0.f};
#pragma unroll
    for (int ks = 0; ks < 16; ks += 2) {
        s16x8 bfr0 = *(const s16x8*)(b3p + (size_t)ks * 512);
        s16x8 bfr1 = *(const s16x8*)(b3p + (size_t)(ks + 1) * 512);
        s16x8 af0 = *(const s16x8*)(smem + hswz(mh * 16 + ln, ks * 32 + g * 8));
        s16x8 af1 = *(const s16x8*)(smem + hswz(mh * 16 + ln, (ks + 1) * 32 + g * 8));
        acc3a = MFMA16(af0, bfr0, acc3a);
        acc3b = MFMA16(af1, bfr1, acc3b);
    }
    __syncthreads();

    // logits + zero-padded a-tile (overlay HBUF, now dead)
    const int LOGB = 0, ABUF = 8704, LST = 272, AST = 544;
#pragma unroll
    for (int r = 0; r < 4; r++) {
        int row = mh * 16 + g * 4 + r;
        *(float*)(smem + LOGB + row * LST + (q * 16 + ln) * 4) = acc3a[r] + acc3b[r] + b3v;
    }
    {
        int r = t >> 4, c0 = (t & 15) * 4;
        float* ap = (float*)(smem + ABUF + r * AST);
        float4 z4 = {0.f, 0.f, 0.f, 0.f};
        *(float4*)(ap + c0) = z4;
        float4 av = *(const float4*)(a_bits + (size_t)(row0 + r) * 64 + c0);
        *(float4*)(ap + 64 + c0) = av;
    }
    __syncthreads();

    // softmax over 64 (16 thr/row)
    {
        int r = t >> 4, c0 = (t & 15) * 4;
        float* lp = (float*)(smem + LOGB + r * LST + c0 * 4);
        float4 v = *(float4*)lp;
        float mx = fmaxf(fmaxf(v.x, v.y), fmaxf(v.z, v.w));
#pragma unroll
        for (int d = 1; d < 16; d <<= 1) mx = fmaxf(mx, __shfl_xor(mx, d, 64));
        float e0 = __expf(v.x - mx), e1 = __expf(v.y - mx);
        float e2 = __expf(v.z - mx), e3 = __expf(v.w - mx);
        float s = e0 + e1 + e2 + e3;
#pragma unroll
        for (int d = 1; d < 16; d <<= 1) s += __shfl_xor(s, d, 64);
        float inv = 1.0f / s;
        float4 o; o.x = e0 * inv; o.y = e1 * inv; o.z = e2 * inv; o.w = e3 * inv;
        *(float4*)lp = o;
    }
    __syncthreads();

    // causal conv, 16 thr/row, 4 outs/thread, zero-padded sliding window
    {
        int r = t >> 4, i0 = (t & 15) * 4;
        const float* prow = (const float*)(smem + LOGB + r * LST);
        const float* apad = (const float*)(smem + ABUF + r * AST);
        float W[8];
        {
            float4 wa = *(const float4*)(apad + i0 + 60);
            float4 wb = *(const float4*)(apad + i0 + 64);
            W[0] = wa.x; W[1] = wa.y; W[2] = wa.z; W[3] = wa.w;
            W[4] = wb.x; W[5] = wb.y; W[6] = wb.z; W[7] = wb.w;
        }
        float o0 = 0.f, o1 = 0.f, o2 = 0.f, o3 = 0.f;
#pragma unroll
        for (int s4 = 0; s4 < 16; s4++) {
            float4 p4 = *(const float4*)(prow + 4 * s4);
            o0 = fmaf(p4.x, W[4], fmaf(p4.y, W[3], fmaf(p4.z, W[2], fmaf(p4.w, W[1], o0))));
            o1 = fmaf(p4.x, W[5], fmaf(p4.y, W[4], fmaf(p4.z, W[3], fmaf(p4.w, W[2], o1))));
            o2 = fmaf(p4.x, W[6], fmaf(p4.y, W[5], fmaf(p4.z, W[4], fmaf(p4.w, W[3], o2))));
            o3 = fmaf(p4.x, W[7], fmaf(p4.y, W[6], fmaf(p4.z, W[5], fmaf(p4.w, W[4], o3))));
            if (s4 < 15) {
                W[4] = W[0]; W[5] = W[1]; W[6] = W[2]; W[7] = W[3];
                float4 nw = *(const float4*)(apad + i0 + 56 - 4 * s4);
                W[0] = nw.x; W[1] = nw.y; W[2] = nw.z; W[3] = nw.w;
            }
        }
        float4 o; o.x = o0; o.y = o1; o.z = o2; o.w = o3;
        *(float4*)(out + (size_t)(row0 + r) * 64 + i0) = o;
    }
}

extern "C" void kernel_launch(void* const* d_in, const int* in_sizes, int n_in,
                              void* d_out, int out_size, void* d_ws, size_t ws_size,
                              hipStream_t stream) {
    const float* a_bits = (const float*)d_in[0];
    const float* shift  = (const float*)d_in[1];
    const float* W1  = (const float*)d_in[2];
    const float* b1  = (const float*)d_in[3];
    const float* g1  = (const float*)d_in[4];
    const float* be1 = (const float*)d_in[5];
    const float* W2  = (const float*)d_in[6];
    const float* b2  = (const float*)d_in[7];
    const float* g2  = (const float*)d_in[8];
    const float* be2 = (const float*)d_in[9];
    const float* W3  = (const float*)d_in[10];
    const float* b3  = (const float*)d_in[11];
    float* out = (float*)d_out;

    // workspace: wt [0,655360) | h1
    char* ws = (char*)d_ws;
    unsigned short* wt = (unsigned short*)ws;

    int CH = 1;
    while (CH < 32) {
        size_t need = 655360ull + 1024ull * (size_t)(BATCH / CH);
        if (need <= ws_size) break;
        CH *= 2;
    }
    const int chunk = BATCH / CH;
    unsigned short* h1 = (unsigned short*)(ws + 655360);

    weights_frag<<<640, 64, 0, stream>>>(W1, W2, W3, wt);
    for (int c = 0; c < CH; c++) {
        int rowoff = c * chunk;
        k1_gemm1<<<chunk / BM, NT, 0, stream>>>(shift, b1, g1, be1, wt, h1, rowoff);
        k23_fused<<<chunk / BM, NT, 0, stream>>>(h1, a_bits, b2, g2, be2, b3, wt, out, rowoff);
    }
}

// Round 14
// 142.302 us; speedup vs baseline: 1.8790x; 1.0137x over previous
//
#include <hip/hip_runtime.h>
#include <hip/hip_bf16.h>
#include <math.h>

// ---------------- problem constants ----------------
#define BATCH 65536
#define NT 512
#define BM 32

using f32x4 = __attribute__((ext_vector_type(4))) float;
using s16x8 = __attribute__((ext_vector_type(8))) short;

#define MFMA16(a, b, c) __builtin_amdgcn_mfma_f32_16x16x32_bf16((a), (b), (c), 0, 0, 0)

__device__ __forceinline__ unsigned short f2bf(float f) {
    unsigned u = __builtin_bit_cast(unsigned, f);
    u = u + 0x7FFFu + ((u >> 16) & 1u);   // RNE
    return (unsigned short)(u >> 16);
}

// A&S 7.1.26 erf, branchless, err 1.5e-7
__device__ __forceinline__ float fast_erf(float x) {
    float ax = fabsf(x);
    float t = __builtin_amdgcn_rcpf(fmaf(0.3275911f, ax, 1.0f));
    float poly = t * fmaf(t, fmaf(t, fmaf(t, fmaf(t, 1.061405429f, -1.453152027f),
                                          1.421413741f), -0.284496736f), 0.254829592f);
    float r = 1.0f - poly * __expf(-ax * ax);
    return copysignf(r, x);
}
__device__ __forceinline__ float gelu(float y) {
    return 0.5f * y * (1.0f + fast_erf(y * 0.70710678118654752f));
}

// swizzled LDS addressing: HBUF rows 1024B; 16B granule XOR (row&7)
__device__ __forceinline__ int hswz(int row, int k) {
    return row * 1024 + ((((k >> 3) ^ (row & 7))) << 4) + ((k & 7) << 1);
}
__device__ __forceinline__ int xaddr(int base, int row, int k) {
    return base + row * 128 + ((((k >> 3) ^ (row & 7))) << 4) + ((k & 7) << 1);
}

// ---------------- weights prep: fragment-linearized bf16 layout ----------------
// frag(nt, ks) element(lane, e) = W[k = ks*32 + (lane>>4)*8 + e][n = nt*16 + (lane&15)]
// dst[(fragidx*64 + lane)*8 + e]  -> one 1KB coalesced block per fragment.
__global__ void weights_frag(const float* __restrict__ W1, const float* __restrict__ W2,
                             const float* __restrict__ W3, unsigned short* __restrict__ wt) {
    int b = blockIdx.x;
    int lane = threadIdx.x;                 // 64 threads
    const float* src; unsigned short* dst; int N, fragidx;
    if (b < 64)       { src = W1; dst = wt;          N = 512; fragidx = b; }
    else if (b < 576) { src = W2; dst = wt + 32768;  N = 512; fragidx = b - 64; }
    else              { src = W3; dst = wt + 294912; N = 64;  fragidx = b - 576; }
    int nt, ks;
    if (b < 64) { nt = fragidx >> 1; ks = fragidx & 1; }
    else        { nt = fragidx >> 4; ks = fragidx & 15; }
    int n  = nt * 16 + (lane & 15);
    int k0 = ks * 32 + (lane >> 4) * 8;
    unsigned short o[8];
#pragma unroll
    for (int e = 0; e < 8; e++) o[e] = f2bf(src[(size_t)(k0 + e) * N + n]);
    *(uint4*)(dst + ((size_t)fragidx * 64 + lane) * 8) = *(uint4*)o;
}

// ---------------- shared LN partial helper (8 waves) ----------------
__device__ __forceinline__ void ln_partials(f32x4 (&acc)[2][4], char* smem, int redb,
                                            int ln, int g, int wave) {
#pragma unroll
    for (int fm = 0; fm < 2; fm++)
#pragma unroll
        for (int r = 0; r < 4; r++) {
            float s = 0.f, q = 0.f;
#pragma unroll
            for (int fn = 0; fn < 4; fn++) { float v = acc[fm][fn][r]; s += v; q += v * v; }
#pragma unroll
            for (int m = 1; m < 16; m <<= 1) { s += __shfl_xor(s, m, 64); q += __shfl_xor(q, m, 64); }
            if (ln == 0) {
                int row = fm * 16 + g * 4 + r;
                float* rp = (float*)(smem + redb + (row * 8 + wave) * 8);
                rp[0] = s; rp[1] = q;
            }
        }
}

// =========================================================================
// K123: GEMM1+LN1+GELU -> (LDS) -> GEMM2+LN2+GELU -> (LDS) -> GEMM3
//       -> softmax -> causal conv -> out.  No intermediate HBM traffic.
// (512,4): sequential phases reuse acc[2][4]; est. peak ~96 unified <= 128.
// LDS: HBUF 32KB @0 | XBUF @32768 (4KB) | RB @36864 (2KB) | SB @38912 (256B)
// epilogue overlay of HBUF: LOGB @0 (32x272B), ABUF @8704 (32x544B)
// =========================================================================
#define SMEM_K123 39168
__global__ __launch_bounds__(NT, 4) void k123_fused(
    const float* __restrict__ shift_bits, const float* __restrict__ a_bits,
    const float* __restrict__ b1, const float* __restrict__ g1, const float* __restrict__ be1,
    const float* __restrict__ b2, const float* __restrict__ g2, const float* __restrict__ be2,
    const float* __restrict__ b3, const unsigned short* __restrict__ wt,
    float* __restrict__ out) {
    __shared__ char smem[SMEM_K123];
    const int t = threadIdx.x;
    const int wave = t >> 6, lane = t & 63, g = lane >> 4, ln = lane & 15;
    const int row0 = blockIdx.x * BM;
    const int n0w = wave * 64;
    const int XB = 32768, RB = 36864, SB = 38912;
    const unsigned short* wt1f = wt;
    const unsigned short* wt2f = wt + 32768;
    const unsigned short* wt3f = wt + 294912;

    // ---- stage shift_bits (32x64 f32 -> bf16, swizzled 128B rows) ----
    {
        int r = t >> 4, c = t & 15;
        float4 x = *(const float4*)(shift_bits + (size_t)(row0 + r) * 64 + c * 4);
        unsigned p0 = (unsigned)f2bf(x.x) | ((unsigned)f2bf(x.y) << 16);
        unsigned p1 = (unsigned)f2bf(x.z) | ((unsigned)f2bf(x.w) << 16);
        uint2 v; v.x = p0; v.y = p1;
        *(uint2*)(smem + XB + r * 128 + (((c >> 1) ^ (r & 7)) << 4) + (c & 1) * 8) = v;
    }
    __syncthreads();

    // ---- GEMM1: x(32x64) @ W1(64x512) -> acc[2][4] ----
    f32x4 acc[2][4];
#pragma unroll
    for (int fm = 0; fm < 2; fm++)
#pragma unroll
        for (int fn = 0; fn < 4; fn++) acc[fm][fn] = (f32x4){0.f, 0.f, 0.f, 0.f};
#pragma unroll
    for (int ks = 0; ks < 2; ks++) {
        s16x8 af[2], bf[4];
#pragma unroll
        for (int fn = 0; fn < 4; fn++) {
            int fragidx = (wave * 4 + fn) * 2 + ks;
            bf[fn] = *(const s16x8*)(wt1f + ((size_t)fragidx * 64 + lane) * 8);
        }
#pragma unroll
        for (int fm = 0; fm < 2; fm++)
            af[fm] = *(const s16x8*)(smem + xaddr(XB, fm * 16 + ln, ks * 32 + g * 8));
#pragma unroll
        for (int fm = 0; fm < 2; fm++)
#pragma unroll
            for (int fn = 0; fn < 4; fn++) acc[fm][fn] = MFMA16(af[fm], bf[fn], acc[fm][fn]);
    }

    // ---- LN1 + GELU -> HBUF ----
    {
        float bb[4];
#pragma unroll
        for (int fn = 0; fn < 4; fn++) bb[fn] = b1[n0w + fn * 16 + ln];
#pragma unroll
        for (int fm = 0; fm < 2; fm++)
#pragma unroll
            for (int fn = 0; fn < 4; fn++)
#pragma unroll
                for (int r = 0; r < 4; r++) acc[fm][fn][r] += bb[fn];
    }
    ln_partials(acc, smem, RB, ln, g, wave);
    __syncthreads();
    if (t < 32) {
        float s = 0.f, q = 0.f;
#pragma unroll
        for (int w = 0; w < 8; w++) {
            float* rp = (float*)(smem + RB + (t * 8 + w) * 8);
            s += rp[0]; q += rp[1];
        }
        float mu = s * (1.0f / 512.0f);
        float var = q * (1.0f / 512.0f) - mu * mu;
        float rs = rsqrtf(var + 1e-5f);
        float* sp = (float*)(smem + SB + t * 8);
        sp[0] = mu; sp[1] = rs;
    }
    __syncthreads();
    {
        float gm[4], bt[4];
#pragma unroll
        for (int fn = 0; fn < 4; fn++) { int c = n0w + fn * 16 + ln; gm[fn] = g1[c]; bt[fn] = be1[c]; }
#pragma unroll
        for (int fm = 0; fm < 2; fm++)
#pragma unroll
            for (int r = 0; r < 4; r++) {
                int row = fm * 16 + g * 4 + r;
                float* sp = (float*)(smem + SB + row * 8);
                float mu = sp[0], rs = sp[1];
#pragma unroll
                for (int fn = 0; fn < 4; fn++) {
                    int col = n0w + fn * 16 + ln;
                    float y = (acc[fm][fn][r] - mu) * rs * gm[fn] + bt[fn];
                    *(unsigned short*)(smem + hswz(row, col)) = f2bf(gelu(y));
                }
            }
    }
    __syncthreads();

    // ---- GEMM2: h1(32x512) @ W2, depth-2 register pipeline on B ----
    const unsigned short* bp[4];
#pragma unroll
    for (int fn = 0; fn < 4; fn++)
        bp[fn] = wt2f + ((size_t)(wave * 4 + fn) * 16 * 64 + lane) * 8;
#pragma unroll
    for (int fm = 0; fm < 2; fm++)
#pragma unroll
        for (int fn = 0; fn < 4; fn++) acc[fm][fn] = (f32x4){0.f, 0.f, 0.f, 0.f};
    {
        s16x8 bcur[4], bnxt[4];
#pragma unroll
        for (int fn = 0; fn < 4; fn++) bcur[fn] = *(const s16x8*)(bp[fn]);
#pragma unroll
        for (int step = 0; step < 16; step++) {
            if (step < 15) {
#pragma unroll
                for (int fn = 0; fn < 4; fn++)
                    bnxt[fn] = *(const s16x8*)(bp[fn] + (size_t)(step + 1) * 512);
            }
            s16x8 af[2];
#pragma unroll
            for (int fm = 0; fm < 2; fm++)
                af[fm] = *(const s16x8*)(smem + hswz(fm * 16 + ln, step * 32 + g * 8));
#pragma unroll
            for (int fm = 0; fm < 2; fm++)
#pragma unroll
                for (int fn = 0; fn < 4; fn++) acc[fm][fn] = MFMA16(af[fm], bcur[fn], acc[fm][fn]);
#pragma unroll
            for (int fn = 0; fn < 4; fn++) bcur[fn] = bnxt[fn];
        }
    }

    // ---- LN2 + GELU -> HBUF (h2 lives only in LDS) ----
    {
        float bb[4];
#pragma unroll
        for (int fn = 0; fn < 4; fn++) bb[fn] = b2[n0w + fn * 16 + ln];
#pragma unroll
        for (int fm = 0; fm < 2; fm++)
#pragma unroll
            for (int fn = 0; fn < 4; fn++)
#pragma unroll
                for (int r = 0; r < 4; r++) acc[fm][fn][r] += bb[fn];
    }
    ln_partials(acc, smem, RB, ln, g, wave);
    __syncthreads();   // all GEMM2 A-reads of HBUF done
    if (t < 32) {
        float s = 0.f, q = 0.f;
#pragma unroll
        for (int w = 0; w < 8; w++) {
            float* rp = (float*)(smem + RB + (t * 8 + w) * 8);
            s += rp[0]; q += rp[1];
        }
        float mu = s * (1.0f / 512.0f);
        float var = q * (1.0f / 512.0f) - mu * mu;
        float rs = rsqrtf(var + 1e-5f);
        float* sp = (float*)(smem + SB + t * 8);
        sp[0] = mu; sp[1] = rs;
    }
    __syncthreads();
    {
        float gm[4], bt[4];
#pragma unroll
        for (int fn = 0; fn < 4; fn++) { int c = n0w + fn * 16 + ln; gm[fn] = g2[c]; bt[fn] = be2[c]; }
#pragma unroll
        for (int fm = 0; fm < 2; fm++)
#pragma unroll
            for (int r = 0; r < 4; r++) {
                int row = fm * 16 + g * 4 + r;
                float* sp = (float*)(smem + SB + row * 8);
                float mu = sp[0], rs = sp[1];
#pragma unroll
                for (int fn = 0; fn < 4; fn++) {
                    int col = n0w + fn * 16 + ln;
                    float y = (acc[fm][fn][r] - mu) * rs * gm[fn] + bt[fn];
                    *(unsigned short*)(smem + hswz(row, col)) = f2bf(gelu(y));
                }
            }
    }
    __syncthreads();

    // ---- GEMM3: h2(32x512) @ W3(512x64); wave (mh,q) owns 16x16 tile; dual acc ----
    const int mh = wave >> 2, q = wave & 3;
    float b3v = b3[q * 16 + ln];
    const unsigned short* b3p = wt3f + ((size_t)q * 16 * 64 + lane) * 8;
    f32x4 acc3a = (f32x4){0.f, 0.f, 0.f, 0.f};
    f32x4 acc3b = (f32x4){0.f, 0.f, 0.f, 0.f};
#pragma unroll
    for (int ks = 0; ks < 16; ks += 2) {
        s16x8 bfr0 = *(const s16x8*)(b3p + (size_t)ks * 512);
        s16x8 bfr1 = *(const s16x8*)(b3p + (size_t)(ks + 1) * 512);
        s16x8 af0 = *(const s16x8*)(smem + hswz(mh * 16 + ln, ks * 32 + g * 8));
        s16x8 af1 = *(const s16x8*)(smem + hswz(mh * 16 + ln, (ks + 1) * 32 + g * 8));
        acc3a = MFMA16(af0, bfr0, acc3a);
        acc3b = MFMA16(af1, bfr1, acc3b);
    }
    __syncthreads();

    // ---- logits + zero-padded a-tile (overlay HBUF, now dead) ----
    const int LOGB = 0, ABUF = 8704, LST = 272, AST = 544;
#pragma unroll
    for (int r = 0; r < 4; r++) {
        int row = mh * 16 + g * 4 + r;
        *(float*)(smem + LOGB + row * LST + (q * 16 + ln) * 4) = acc3a[r] + acc3b[r] + b3v;
    }
    {
        int r = t >> 4, c0 = (t & 15) * 4;
        float* ap = (float*)(smem + ABUF + r * AST);
        float4 z4 = {0.f, 0.f, 0.f, 0.f};
        *(float4*)(ap + c0) = z4;
        float4 av = *(const float4*)(a_bits + (size_t)(row0 + r) * 64 + c0);
        *(float4*)(ap + 64 + c0) = av;
    }
    __syncthreads();

    // ---- softmax over 64 (16 thr/row) ----
    {
        int r = t >> 4, c0 = (t & 15) * 4;
        float* lp = (float*)(smem + LOGB + r * LST + c0 * 4);
        float4 v = *(float4*)lp;
        float mx = fmaxf(fmaxf(v.x, v.y), fmaxf(v.z, v.w));
#pragma unroll
        for (int d = 1; d < 16; d <<= 1) mx = fmaxf(mx, __shfl_xor(mx, d, 64));
        float e0 = __expf(v.x - mx), e1 = __expf(v.y - mx);
        float e2 = __expf(v.z - mx), e3 = __expf(v.w - mx);
        float s = e0 + e1 + e2 + e3;
#pragma unroll
        for (int d = 1; d < 16; d <<= 1) s += __shfl_xor(s, d, 64);
        float inv = 1.0f / s;
        float4 o; o.x = e0 * inv; o.y = e1 * inv; o.z = e2 * inv; o.w = e3 * inv;
        *(float4*)lp = o;
    }
    __syncthreads();

    // ---- causal conv, 16 thr/row, 4 outs/thread, zero-padded sliding window ----
    {
        int r = t >> 4, i0 = (t & 15) * 4;
        const float* prow = (const float*)(smem + LOGB + r * LST);
        const float* apad = (const float*)(smem + ABUF + r * AST);
        float W[8];
        {
            float4 wa = *(const float4*)(apad + i0 + 60);
            float4 wb = *(const float4*)(apad + i0 + 64);
            W[0] = wa.x; W[1] = wa.y; W[2] = wa.z; W[3] = wa.w;
            W[4] = wb.x; W[5] = wb.y; W[6] = wb.z; W[7] = wb.w;
        }
        float o0 = 0.f, o1 = 0.f, o2 = 0.f, o3 = 0.f;
#pragma unroll
        for (int s4 = 0; s4 < 16; s4++) {
            float4 p4 = *(const float4*)(prow + 4 * s4);
            o0 = fmaf(p4.x, W[4], fmaf(p4.y, W[3], fmaf(p4.z, W[2], fmaf(p4.w, W[1], o0))));
            o1 = fmaf(p4.x, W[5], fmaf(p4.y, W[4], fmaf(p4.z, W[3], fmaf(p4.w, W[2], o1))));
            o2 = fmaf(p4.x, W[6], fmaf(p4.y, W[5], fmaf(p4.z, W[4], fmaf(p4.w, W[3], o2))));
            o3 = fmaf(p4.x, W[7], fmaf(p4.y, W[6], fmaf(p4.z, W[5], fmaf(p4.w, W[4], o3))));
            if (s4 < 15) {
                W[4] = W[0]; W[5] = W[1]; W[6] = W[2]; W[7] = W[3];
                float4 nw = *(const float4*)(apad + i0 + 56 - 4 * s4);
                W[0] = nw.x; W[1] = nw.y; W[2] = nw.z; W[3] = nw.w;
            }
        }
        float4 o; o.x = o0; o.y = o1; o.z = o2; o.w = o3;
        *(float4*)(out + (size_t)(row0 + r) * 64 + i0) = o;
    }
}

extern "C" void kernel_launch(void* const* d_in, const int* in_sizes, int n_in,
                              void* d_out, int out_size, void* d_ws, size_t ws_size,
                              hipStream_t stream) {
    const float* a_bits = (const float*)d_in[0];
    const float* shift  = (const float*)d_in[1];
    const float* W1  = (const float*)d_in[2];
    const float* b1  = (const float*)d_in[3];
    const float* g1  = (const float*)d_in[4];
    const float* be1 = (const float*)d_in[5];
    const float* W2  = (const float*)d_in[6];
    const float* b2  = (const float*)d_in[7];
    const float* g2  = (const float*)d_in[8];
    const float* be2 = (const float*)d_in[9];
    const float* W3  = (const float*)d_in[10];
    const float* b3  = (const float*)d_in[11];
    float* out = (float*)d_out;
    unsigned short* wt = (unsigned short*)d_ws;

    weights_frag<<<640, 64, 0, stream>>>(W1, W2, W3, wt);
    k123_fused<<<BATCH / BM, NT, 0, stream>>>(shift, a_bits, b1, g1, be1,
                                              b2, g2, be2, b3, wt, out);
}

// Round 15
// 138.901 us; speedup vs baseline: 1.9250x; 1.0245x over previous
//
#include <hip/hip_runtime.h>
#include <hip/hip_bf16.h>
#include <math.h>

// ---------------- problem constants ----------------
#define BATCH 65536
#define NT 512
#define BM 32

using f32x4 = __attribute__((ext_vector_type(4))) float;
using s16x8 = __attribute__((ext_vector_type(8))) short;

#define MFMA16(a, b, c) __builtin_amdgcn_mfma_f32_16x16x32_bf16((a), (b), (c), 0, 0, 0)

__device__ __forceinline__ unsigned short f2bf(float f) {
    unsigned u = __builtin_bit_cast(unsigned, f);
    u = u + 0x7FFFu + ((u >> 16) & 1u);   // RNE
    return (unsigned short)(u >> 16);
}

// A&S 7.1.26 erf, branchless, err 1.5e-7
__device__ __forceinline__ float fast_erf(float x) {
    float ax = fabsf(x);
    float t = __builtin_amdgcn_rcpf(fmaf(0.3275911f, ax, 1.0f));
    float poly = t * fmaf(t, fmaf(t, fmaf(t, fmaf(t, 1.061405429f, -1.453152027f),
                                          1.421413741f), -0.284496736f), 0.254829592f);
    float r = 1.0f - poly * __expf(-ax * ax);
    return copysignf(r, x);
}
__device__ __forceinline__ float gelu(float y) {
    return 0.5f * y * (1.0f + fast_erf(y * 0.70710678118654752f));
}

// swizzled LDS addressing: HBUF rows 1024B; 16B granule XOR (row&7)
__device__ __forceinline__ int hswz(int row, int k) {
    return row * 1024 + ((((k >> 3) ^ (row & 7))) << 4) + ((k & 7) << 1);
}
__device__ __forceinline__ int xaddr(int base, int row, int k) {
    return base + row * 128 + ((((k >> 3) ^ (row & 7))) << 4) + ((k & 7) << 1);
}

// ---------------- weights prep: fragment-linearized bf16 layout ----------------
// frag(nt, ks) element(lane, e) = W[k = ks*32 + (lane>>4)*8 + e][n = nt*16 + (lane&15)]
// dst[(fragidx*64 + lane)*8 + e]  -> one 1KB coalesced block per fragment.
__global__ void weights_frag(const float* __restrict__ W1, const float* __restrict__ W2,
                             const float* __restrict__ W3, unsigned short* __restrict__ wt) {
    int b = blockIdx.x;
    int lane = threadIdx.x;                 // 64 threads
    const float* src; unsigned short* dst; int N, fragidx;
    if (b < 64)       { src = W1; dst = wt;          N = 512; fragidx = b; }
    else if (b < 576) { src = W2; dst = wt + 32768;  N = 512; fragidx = b - 64; }
    else              { src = W3; dst = wt + 294912; N = 64;  fragidx = b - 576; }
    int nt, ks;
    if (b < 64) { nt = fragidx >> 1; ks = fragidx & 1; }
    else        { nt = fragidx >> 4; ks = fragidx & 15; }
    int n  = nt * 16 + (lane & 15);
    int k0 = ks * 32 + (lane >> 4) * 8;
    unsigned short o[8];
#pragma unroll
    for (int e = 0; e < 8; e++) o[e] = f2bf(src[(size_t)(k0 + e) * N + n]);
    *(uint4*)(dst + ((size_t)fragidx * 64 + lane) * 8) = *(uint4*)o;
}

// ---------------- shared LN partial helper (8 waves) ----------------
__device__ __forceinline__ void ln_partials(f32x4 (&acc)[2][4], char* smem, int redb,
                                            int ln, int g, int wave) {
#pragma unroll
    for (int fm = 0; fm < 2; fm++)
#pragma unroll
        for (int r = 0; r < 4; r++) {
            float s = 0.f, q = 0.f;
#pragma unroll
            for (int fn = 0; fn < 4; fn++) { float v = acc[fm][fn][r]; s += v; q += v * v; }
#pragma unroll
            for (int m = 1; m < 16; m <<= 1) { s += __shfl_xor(s, m, 64); q += __shfl_xor(q, m, 64); }
            if (ln == 0) {
                int row = fm * 16 + g * 4 + r;
                float* rp = (float*)(smem + redb + (row * 8 + wave) * 8);
                rp[0] = s; rp[1] = q;
            }
        }
}

// =========================================================================
// K123 v2: fully fused, register-dieted (no GEMM2 pipeline buffer, single
// weight base pointer). Goal: fit 64 arch VGPRs -> zero spill at (512,4).
// LDS: HBUF 32KB @0 | XBUF @32768 (4KB) | RB @36864 (2KB) | SB @38912 (256B)
// epilogue overlay of HBUF: LOGB @0 (32x272B), ABUF @8704 (32x544B)
// =========================================================================
#define SMEM_K123 39168
__global__ __launch_bounds__(NT, 4) void k123_fused(
    const float* __restrict__ shift_bits, const float* __restrict__ a_bits,
    const float* __restrict__ b1, const float* __restrict__ g1, const float* __restrict__ be1,
    const float* __restrict__ b2, const float* __restrict__ g2, const float* __restrict__ be2,
    const float* __restrict__ b3, const unsigned short* __restrict__ wt,
    float* __restrict__ out) {
    __shared__ char smem[SMEM_K123];
    const int t = threadIdx.x;
    const int wave = t >> 6, lane = t & 63, g = lane >> 4, ln = lane & 15;
    const int row0 = blockIdx.x * BM;
    const int n0w = wave * 64;
    const int XB = 32768, RB = 36864, SB = 38912;

    // ---- stage shift_bits (32x64 f32 -> bf16, swizzled 128B rows) ----
    {
        int r = t >> 4, c = t & 15;
        float4 x = *(const float4*)(shift_bits + (size_t)(row0 + r) * 64 + c * 4);
        unsigned p0 = (unsigned)f2bf(x.x) | ((unsigned)f2bf(x.y) << 16);
        unsigned p1 = (unsigned)f2bf(x.z) | ((unsigned)f2bf(x.w) << 16);
        uint2 v; v.x = p0; v.y = p1;
        *(uint2*)(smem + XB + r * 128 + (((c >> 1) ^ (r & 7)) << 4) + (c & 1) * 8) = v;
    }
    __syncthreads();

    // ---- GEMM1: x(32x64) @ W1(64x512) -> acc[2][4] ----
    // single per-lane W1 base: frag (wave*8 + fn*2 + ks), each 512 elems
    const unsigned short* w1base = wt + ((size_t)wave * 8 * 64 + lane) * 8;
    f32x4 acc[2][4];
#pragma unroll
    for (int fm = 0; fm < 2; fm++)
#pragma unroll
        for (int fn = 0; fn < 4; fn++) acc[fm][fn] = (f32x4){0.f, 0.f, 0.f, 0.f};
#pragma unroll
    for (int ks = 0; ks < 2; ks++) {
        s16x8 af[2], bf[4];
#pragma unroll
        for (int fn = 0; fn < 4; fn++)
            bf[fn] = *(const s16x8*)(w1base + (size_t)(fn * 2 + ks) * 512);
#pragma unroll
        for (int fm = 0; fm < 2; fm++)
            af[fm] = *(const s16x8*)(smem + xaddr(XB, fm * 16 + ln, ks * 32 + g * 8));
#pragma unroll
        for (int fm = 0; fm < 2; fm++)
#pragma unroll
            for (int fn = 0; fn < 4; fn++) acc[fm][fn] = MFMA16(af[fm], bf[fn], acc[fm][fn]);
    }

    // ---- LN1 + GELU -> HBUF ----
    {
        float bb[4];
#pragma unroll
        for (int fn = 0; fn < 4; fn++) bb[fn] = b1[n0w + fn * 16 + ln];
#pragma unroll
        for (int fm = 0; fm < 2; fm++)
#pragma unroll
            for (int fn = 0; fn < 4; fn++)
#pragma unroll
                for (int r = 0; r < 4; r++) acc[fm][fn][r] += bb[fn];
    }
    ln_partials(acc, smem, RB, ln, g, wave);
    __syncthreads();
    if (t < 32) {
        float s = 0.f, q = 0.f;
#pragma unroll
        for (int w = 0; w < 8; w++) {
            float* rp = (float*)(smem + RB + (t * 8 + w) * 8);
            s += rp[0]; q += rp[1];
        }
        float mu = s * (1.0f / 512.0f);
        float var = q * (1.0f / 512.0f) - mu * mu;
        float rs = rsqrtf(var + 1e-5f);
        float* sp = (float*)(smem + SB + t * 8);
        sp[0] = mu; sp[1] = rs;
    }
    __syncthreads();
    {
        float gm[4], bt[4];
#pragma unroll
        for (int fn = 0; fn < 4; fn++) { int c = n0w + fn * 16 + ln; gm[fn] = g1[c]; bt[fn] = be1[c]; }
#pragma unroll
        for (int fm = 0; fm < 2; fm++)
#pragma unroll
            for (int r = 0; r < 4; r++) {
                int row = fm * 16 + g * 4 + r;
                float* sp = (float*)(smem + SB + row * 8);
                float mu = sp[0], rs = sp[1];
#pragma unroll
                for (int fn = 0; fn < 4; fn++) {
                    int col = n0w + fn * 16 + ln;
                    float y = (acc[fm][fn][r] - mu) * rs * gm[fn] + bt[fn];
                    *(unsigned short*)(smem + hswz(row, col)) = f2bf(gelu(y));
                }
            }
    }
    __syncthreads();

    // ---- GEMM2: h1(32x512) @ W2, depth-1 coalesced frag loads ----
    // single per-lane W2 base: frag (wave*64 + fn*16 + step), each 512 elems
    const unsigned short* w2base = wt + 32768 + ((size_t)wave * 64 * 64 + lane) * 8;
#pragma unroll
    for (int fm = 0; fm < 2; fm++)
#pragma unroll
        for (int fn = 0; fn < 4; fn++) acc[fm][fn] = (f32x4){0.f, 0.f, 0.f, 0.f};
#pragma unroll
    for (int step = 0; step < 16; step++) {
        s16x8 bf[4], af[2];
#pragma unroll
        for (int fn = 0; fn < 4; fn++)
            bf[fn] = *(const s16x8*)(w2base + (size_t)(fn * 16 + step) * 512);
#pragma unroll
        for (int fm = 0; fm < 2; fm++)
            af[fm] = *(const s16x8*)(smem + hswz(fm * 16 + ln, step * 32 + g * 8));
#pragma unroll
        for (int fm = 0; fm < 2; fm++)
#pragma unroll
            for (int fn = 0; fn < 4; fn++) acc[fm][fn] = MFMA16(af[fm], bf[fn], acc[fm][fn]);
    }

    // ---- LN2 + GELU -> HBUF (h2 lives only in LDS) ----
    {
        float bb[4];
#pragma unroll
        for (int fn = 0; fn < 4; fn++) bb[fn] = b2[n0w + fn * 16 + ln];
#pragma unroll
        for (int fm = 0; fm < 2; fm++)
#pragma unroll
            for (int fn = 0; fn < 4; fn++)
#pragma unroll
                for (int r = 0; r < 4; r++) acc[fm][fn][r] += bb[fn];
    }
    ln_partials(acc, smem, RB, ln, g, wave);
    __syncthreads();   // all GEMM2 A-reads of HBUF done
    if (t < 32) {
        float s = 0.f, q = 0.f;
#pragma unroll
        for (int w = 0; w < 8; w++) {
            float* rp = (float*)(smem + RB + (t * 8 + w) * 8);
            s += rp[0]; q += rp[1];
        }
        float mu = s * (1.0f / 512.0f);
        float var = q * (1.0f / 512.0f) - mu * mu;
        float rs = rsqrtf(var + 1e-5f);
        float* sp = (float*)(smem + SB + t * 8);
        sp[0] = mu; sp[1] = rs;
    }
    __syncthreads();
    {
        float gm[4], bt[4];
#pragma unroll
        for (int fn = 0; fn < 4; fn++) { int c = n0w + fn * 16 + ln; gm[fn] = g2[c]; bt[fn] = be2[c]; }
#pragma unroll
        for (int fm = 0; fm < 2; fm++)
#pragma unroll
            for (int r = 0; r < 4; r++) {
                int row = fm * 16 + g * 4 + r;
                float* sp = (float*)(smem + SB + row * 8);
                float mu = sp[0], rs = sp[1];
#pragma unroll
                for (int fn = 0; fn < 4; fn++) {
                    int col = n0w + fn * 16 + ln;
                    float y = (acc[fm][fn][r] - mu) * rs * gm[fn] + bt[fn];
                    *(unsigned short*)(smem + hswz(row, col)) = f2bf(gelu(y));
                }
            }
    }
    __syncthreads();

    // ---- GEMM3: h2(32x512) @ W3(512x64); wave (mh,q) owns 16x16 tile; dual acc ----
    const int mh = wave >> 2, q = wave & 3;
    float b3v = b3[q * 16 + ln];
    const unsigned short* b3p = wt + 294912 + ((size_t)q * 16 * 64 + lane) * 8;
    f32x4 acc3a = (f32x4){0.f, 0.f, 0.f, 0.f};
    f32x4 acc3b = (f32x4){0.f, 0.f, 0.f, 0.f};
#pragma unroll
    for (int ks = 0; ks < 16; ks += 2) {
        s16x8 bfr0 = *(const s16x8*)(b3p + (size_t)ks * 512);
        s16x8 bfr1 = *(const s16x8*)(b3p + (size_t)(ks + 1) * 512);
        s16x8 af0 = *(const s16x8*)(smem + hswz(mh * 16 + ln, ks * 32 + g * 8));
        s16x8 af1 = *(const s16x8*)(smem + hswz(mh * 16 + ln, (ks + 1) * 32 + g * 8));
        acc3a = MFMA16(af0, bfr0, acc3a);
        acc3b = MFMA16(af1, bfr1, acc3b);
    }
    __syncthreads();

    // ---- logits + zero-padded a-tile (overlay HBUF, now dead) ----
    const int LOGB = 0, ABUF = 8704, LST = 272, AST = 544;
#pragma unroll
    for (int r = 0; r < 4; r++) {
        int row = mh * 16 + g * 4 + r;
        *(float*)(smem + LOGB + row * LST + (q * 16 + ln) * 4) = acc3a[r] + acc3b[r] + b3v;
    }
    {
        int r = t >> 4, c0 = (t & 15) * 4;
        float* ap = (float*)(smem + ABUF + r * AST);
        float4 z4 = {0.f, 0.f, 0.f, 0.f};
        *(float4*)(ap + c0) = z4;
        float4 av = *(const float4*)(a_bits + (size_t)(row0 + r) * 64 + c0);
        *(float4*)(ap + 64 + c0) = av;
    }
    __syncthreads();

    // ---- softmax over 64 (16 thr/row) ----
    {
        int r = t >> 4, c0 = (t & 15) * 4;
        float* lp = (float*)(smem + LOGB + r * LST + c0 * 4);
        float4 v = *(float4*)lp;
        float mx = fmaxf(fmaxf(v.x, v.y), fmaxf(v.z, v.w));
#pragma unroll
        for (int d = 1; d < 16; d <<= 1) mx = fmaxf(mx, __shfl_xor(mx, d, 64));
        float e0 = __expf(v.x - mx), e1 = __expf(v.y - mx);
        float e2 = __expf(v.z - mx), e3 = __expf(v.w - mx);
        float s = e0 + e1 + e2 + e3;
#pragma unroll
        for (int d = 1; d < 16; d <<= 1) s += __shfl_xor(s, d, 64);
        float inv = 1.0f / s;
        float4 o; o.x = e0 * inv; o.y = e1 * inv; o.z = e2 * inv; o.w = e3 * inv;
        *(float4*)lp = o;
    }
    __syncthreads();

    // ---- causal conv, 16 thr/row, 4 outs/thread, zero-padded sliding window ----
    {
        int r = t >> 4, i0 = (t & 15) * 4;
        const float* prow = (const float*)(smem + LOGB + r * LST);
        const float* apad = (const float*)(smem + ABUF + r * AST);
        float W[8];
        {
            float4 wa = *(const float4*)(apad + i0 + 60);
            float4 wb = *(const float4*)(apad + i0 + 64);
            W[0] = wa.x; W[1] = wa.y; W[2] = wa.z; W[3] = wa.w;
            W[4] = wb.x; W[5] = wb.y; W[6] = wb.z; W[7] = wb.w;
        }
        float o0 = 0.f, o1 = 0.f, o2 = 0.f, o3 = 0.f;
#pragma unroll
        for (int s4 = 0; s4 < 16; s4++) {
            float4 p4 = *(const float4*)(prow + 4 * s4);
            o0 = fmaf(p4.x, W[4], fmaf(p4.y, W[3], fmaf(p4.z, W[2], fmaf(p4.w, W[1], o0))));
            o1 = fmaf(p4.x, W[5], fmaf(p4.y, W[4], fmaf(p4.z, W[3], fmaf(p4.w, W[2], o1))));
            o2 = fmaf(p4.x, W[6], fmaf(p4.y, W[5], fmaf(p4.z, W[4], fmaf(p4.w, W[3], o2))));
            o3 = fmaf(p4.x, W[7], fmaf(p4.y, W[6], fmaf(p4.z, W[5], fmaf(p4.w, W[4], o3))));
            if (s4 < 15) {
                W[4] = W[0]; W[5] = W[1]; W[6] = W[2]; W[7] = W[3];
                float4 nw = *(const float4*)(apad + i0 + 56 - 4 * s4);
                W[0] = nw.x; W[1] = nw.y; W[2] = nw.z; W[3] = nw.w;
            }
        }
        float4 o; o.x = o0; o.y = o1; o.z = o2; o.w = o3;
        *(float4*)(out + (size_t)(row0 + r) * 64 + i0) = o;
    }
}

extern "C" void kernel_launch(void* const* d_in, const int* in_sizes, int n_in,
                              void* d_out, int out_size, void* d_ws, size_t ws_size,
                              hipStream_t stream) {
    const float* a_bits = (const float*)d_in[0];
    const float* shift  = (const float*)d_in[1];
    const float* W1  = (const float*)d_in[2];
    const float* b1  = (const float*)d_in[3];
    const float* g1  = (const float*)d_in[4];
    const float* be1 = (const float*)d_in[5];
    const float* W2  = (const float*)d_in[6];
    const float* b2  = (const float*)d_in[7];
    const float* g2  = (const float*)d_in[8];
    const float* be2 = (const float*)d_in[9];
    const float* W3  = (const float*)d_in[10];
    const float* b3  = (const float*)d_in[11];
    float* out = (float*)d_out;
    unsigned short* wt = (unsigned short*)d_ws;

    weights_frag<<<640, 64, 0, stream>>>(W1, W2, W3, wt);
    k123_fused<<<BATCH / BM, NT, 0, stream>>>(shift, a_bits, b1, g1, be1,
                                              b2, g2, be2, b3, wt, out);
}